// Round 7
// baseline (154.210 us; speedup 1.0000x reference)
//
#include <hip/hip_runtime.h>
#include <hip/hip_bf16.h>

typedef _Float16 half8 __attribute__((ext_vector_type(8)));
typedef _Float16 half4 __attribute__((ext_vector_type(4)));
typedef float f32x4 __attribute__((ext_vector_type(4)));

#define B 512
#define D 128
#define K 131072
#define TEMP 0.07f
#define NKB 512      // k-blocks in nnsearch grid
#define KT_PER 16    // 16-wide k-tiles per block (256 cols)

// ws layout in float units
#define INVN_OFF 0
#define Z0_OFF   131072
#define Z1_OFF   196608
#define P0_OFF   262144
#define P1_OFF   327680
#define ZF16_OFF 393216                 // 1024*128 halves = 65536 floats
#define QA_OFF   458752                 // K*D halves = 8388608 floats
#define PVAL_OFF 8847360                // 1024*512 floats
#define WKB_OFF  9371648                // 1024 ints
#define WVAL_OFF 9372672                // 1024 floats
#define IDX_OFF  9373696                // 1024 ints
#define LP_OFF   9374720                // 1024 floats

// Normalize rows of z0, z1, p0, p1 (each B x D) into ws; also z in f16.
__global__ __launch_bounds__(128) void rownorm_k(
    const float* __restrict__ p0, const float* __restrict__ p1,
    const float* __restrict__ z0, const float* __restrict__ z1,
    float* __restrict__ w, _Float16* __restrict__ zf16) {
  int row = blockIdx.x & (B - 1);
  int which = blockIdx.x >> 9;  // 0..3
  const float* src; float* dst;
  switch (which) {
    case 0: src = z0; dst = w + Z0_OFF; break;
    case 1: src = z1; dst = w + Z1_OFF; break;
    case 2: src = p0; dst = w + P0_OFF; break;
    default: src = p1; dst = w + P1_OFF; break;
  }
  int tid = threadIdx.x;
  float v = src[row * D + tid];
  float s = v * v;
  #pragma unroll
  for (int o = 32; o; o >>= 1) s += __shfl_xor(s, o);
  __shared__ float sm[2];
  if ((tid & 63) == 0) sm[tid >> 6] = s;
  __syncthreads();
  float inv = rsqrtf(sm[0] + sm[1]);
  float nv = v * inv;
  dst[row * D + tid] = nv;
  if (which < 2) zf16[(which * B + row) * D + tid] = (_Float16)nv;
}

// Fused, BW-oriented: block owns 128 queue columns.
// Phase 1: float4 loads along k -> column norms (LDS tree reduce).
// Phase 2: L2-hot float4 re-read; scalar new_queue stores (the +1 output
//          offset forbids aligned vector stores); half4 LDS tile writes.
// Phase 3: pack MFMA A-operand fragments (qA) from LDS tile.
__global__ __launch_bounds__(256) void colq_k(
    const float* __restrict__ q, const int* __restrict__ qid,
    const int* __restrict__ ids, const float* __restrict__ w_z0,
    float* __restrict__ invn, float* __restrict__ out,
    _Float16* __restrict__ qA) {
  __shared__ float psum[8][128];
  __shared__ float invs[128];
  __shared__ _Float16 tile[128][136];
  int tid = threadIdx.x;
  int kb = blockIdx.x;           // 0..1023
  int k0 = kb * 128;
  int kc = tid & 31, dg = tid >> 5;
  {
    float4 acc = {0.f, 0.f, 0.f, 0.f};
    for (int i = 0; i < 16; i++) {
      int d = dg * 16 + i;
      float4 v = *(const float4*)(q + (size_t)d * K + k0 + kc * 4);
      acc.x = fmaf(v.x, v.x, acc.x); acc.y = fmaf(v.y, v.y, acc.y);
      acc.z = fmaf(v.z, v.z, acc.z); acc.w = fmaf(v.w, v.w, acc.w);
    }
    *(float4*)&psum[dg][kc * 4] = acc;
  }
  __syncthreads();
  if (tid < 128) {
    float s = 0.f;
    #pragma unroll
    for (int g2 = 0; g2 < 8; g2++) s += psum[g2][tid];
    float inv = rsqrtf(s);
    invs[tid] = inv;
    invn[k0 + tid] = inv;
    int kk = k0 + tid;
    out[1 + (size_t)D * K + kk] = (float)((kk < B) ? ids[kk] : qid[kk]);
  }
  __syncthreads();
  {
    bool zblk = (k0 < B);  // block-uniform: cols come from z0^T
    float4 iv = *(const float4*)&invs[kc * 4];
    for (int i = 0; i < 16; i++) {
      int d = i * 8 + dg;
      float4 v = *(const float4*)(q + (size_t)d * K + k0 + kc * 4);
      float o0 = v.x * iv.x, o1 = v.y * iv.y, o2 = v.z * iv.z, o3 = v.w * iv.w;
      half4 t = {(_Float16)o0, (_Float16)o1, (_Float16)o2, (_Float16)o3};
      *(half4*)&tile[d][kc * 4] = t;
      float* oc = out + 1 + (size_t)d * K + k0 + kc * 4;
      if (zblk) {
        int col = k0 + kc * 4;
        oc[0] = w_z0[(size_t)(col + 0) * D + d];
        oc[1] = w_z0[(size_t)(col + 1) * D + d];
        oc[2] = w_z0[(size_t)(col + 2) * D + d];
        oc[3] = w_z0[(size_t)(col + 3) * D + d];
      } else {
        oc[0] = o0; oc[1] = o1; oc[2] = o2; oc[3] = o3;
      }
    }
  }
  __syncthreads();
  {
    int dc = tid >> 6, l = tid & 63;
    int g = l >> 4, c = l & 15;
    #pragma unroll
    for (int kt = 0; kt < 8; kt++) {
      half8 f;
      #pragma unroll
      for (int i = 0; i < 8; i++) {
        int d = g * 4 + (i & 3) + ((i >> 2) << 4) + dc * 32;
        f[i] = tile[d][kt * 16 + c];
      }
      int ktg = kb * 8 + kt;
      *(half8*)(qA + (size_t)((ktg * 4 + dc) * 64 + l) * 8) = f;
    }
  }
}

#define LOADAF(AF, Q4, KTG) do { \
  _Pragma("unroll") \
  for (int dc = 0; dc < 4; dc++) \
    AF[dc] = *(const half8*)(qA + (size_t)(((KTG) * 4 + dc) * 64 + lane) * 8); \
  Q4 = *(const int4*)(qid + (KTG) * 16 + g * 4); \
} while (0)

// Value-only masked max: 3 VALU ops per element (cmp, cndmask, max).
#define PROCESS(AF, Q4, KTG) do { \
  _Pragma("unroll") \
  for (int nt = 0; nt < 4; nt++) { \
    f32x4 acc = {0.f, 0.f, 0.f, 0.f}; \
    _Pragma("unroll") \
    for (int dc = 0; dc < 4; dc++) \
      acc = __builtin_amdgcn_mfma_f32_16x16x32_f16(AF[dc], bf[nt][dc], acc, 0, 0, 0); \
    _Pragma("unroll") \
    for (int r = 0; r < 4; r++) { \
      int qv_ = (r == 0) ? Q4.x : (r == 1) ? Q4.y : (r == 2) ? Q4.z : Q4.w; \
      float sm_ = (qv_ == myid[nt]) ? -1.0f : acc[r]; \
      best[nt] = fmaxf(best[nt], sm_); \
    } \
  } \
} while (0)

// MFMA NN search pass 1. M = queue index k, N = z-row. Wave owns 64 z-rows
// (B-frags register-resident). XCD-aware decode: the 4 rg-blocks of one kb
// land on the same XCD within a 32-block dispatch window -> qA L2 reuse.
// 4-buffer distance-3 pipeline on qA fragment loads.
__global__ __launch_bounds__(256) void nnsearch_k(
    const _Float16* __restrict__ qA, const _Float16* __restrict__ zf16,
    const int* __restrict__ qid, const int* __restrict__ ids,
    float* __restrict__ pval) {
  int tid = threadIdx.x;
  int flat = blockIdx.x;        // 0..2047
  int cls = flat & 7;           // XCD under round-robin dispatch
  int kb = cls * 64 + (flat >> 5);
  int rg = (flat >> 3) & 3;
  int wave = tid >> 6, lane = tid & 63;
  int g = lane >> 4, c = lane & 15;
  int rowbase = rg * 256 + wave * 64;

  half8 bf[4][4];
  int myid[4];
  #pragma unroll
  for (int nt = 0; nt < 4; nt++) {
    int row = rowbase + nt * 16 + c;
    myid[nt] = ids[row & (B - 1)];
    #pragma unroll
    for (int dc = 0; dc < 4; dc++) {
      const _Float16* zr = zf16 + row * D + dc * 32 + g * 4;
      half4 lo = *(const half4*)zr;
      half4 hi = *(const half4*)(zr + 16);
      half8 f = {lo[0], lo[1], lo[2], lo[3], hi[0], hi[1], hi[2], hi[3]};
      bf[nt][dc] = f;
    }
  }

  float best[4] = {-2.f, -2.f, -2.f, -2.f};
  int kt0 = kb * KT_PER;
  half8 af0[4], af1[4], af2[4], af3[4];
  int4 q40, q41, q42, q43;
  LOADAF(af0, q40, kt0 + 0);
  LOADAF(af1, q41, kt0 + 1);
  LOADAF(af2, q42, kt0 + 2);
  for (int kt = 0; kt < KT_PER; kt += 4) {
    LOADAF(af3, q43, kt0 + kt + 3);
    PROCESS(af0, q40, kt0 + kt);
    if (kt + 4 < KT_PER) LOADAF(af0, q40, kt0 + kt + 4);
    PROCESS(af1, q41, kt0 + kt + 1);
    if (kt + 5 < KT_PER) LOADAF(af1, q41, kt0 + kt + 5);
    PROCESS(af2, q42, kt0 + kt + 2);
    if (kt + 6 < KT_PER) LOADAF(af2, q42, kt0 + kt + 6);
    PROCESS(af3, q43, kt0 + kt + 3);
  }

  #pragma unroll
  for (int nt = 0; nt < 4; nt++) {
    float v = best[nt];
    v = fmaxf(v, __shfl_xor(v, 16));
    v = fmaxf(v, __shfl_xor(v, 32));
    if (g == 0) {
      int row = rowbase + nt * 16 + c;
      pval[row * NKB + kb] = v;
    }
  }
}

// Reduce NKB block-maxima per row -> winning block kb (lowest on ties) + its
// exact value. Lossless pack: t=fma(v,.5,3) in [2.5,3.5] has fixed exponent,
// so bits(t)<<9 preserves full mantissa; low 9 bits carry (511-kb).
__global__ __launch_bounds__(256) void nnreduce_k(
    const float* __restrict__ pval, int* __restrict__ wkb,
    float* __restrict__ wval) {
  int row = blockIdx.x;
  int tid = threadIdx.x;
  const float* p = pval + row * NKB;
  float a = p[tid], b = p[tid + 256];
  unsigned pa = (__float_as_uint(fmaf(a, 0.5f, 3.0f)) << 9) | (unsigned)(511 - tid);
  unsigned pb = (__float_as_uint(fmaf(b, 0.5f, 3.0f)) << 9) | (unsigned)(255 - tid);
  unsigned v = pa > pb ? pa : pb;
  #pragma unroll
  for (int o = 32; o; o >>= 1) {
    unsigned ov = __shfl_xor(v, o);
    v = v > ov ? v : ov;
  }
  __shared__ unsigned sv[4];
  if ((tid & 63) == 0) sv[tid >> 6] = v;
  __syncthreads();
  if (tid == 0) {
    #pragma unroll
    for (int wv = 1; wv < 4; wv++) v = v > sv[wv] ? v : sv[wv];
    int kb = 511 - (int)(v & 0x1FFu);
    wkb[row] = kb;
    wval[row] = pval[row * NKB + kb];
  }
}

// Pass 2: exact index recovery inside the winning block. One wave per row;
// the row is replicated into all 16 B-fragment columns, so MFMA reproduces
// bitwise-identical sims; pick the lowest k with sim == wval.
__global__ __launch_bounds__(256) void nnfix_k(
    const _Float16* __restrict__ qA, const _Float16* __restrict__ zf16,
    const int* __restrict__ qid, const int* __restrict__ ids,
    const int* __restrict__ wkb, const float* __restrict__ wval,
    int* __restrict__ idxout) {
  int tid = threadIdx.x;
  int wave = tid >> 6, lane = tid & 63;
  int g = lane >> 4;
  int row = blockIdx.x * 4 + wave;
  int kb = wkb[row];
  float wv = wval[row];
  int myid = ids[row & (B - 1)];

  half8 bf[4];
  #pragma unroll
  for (int dc = 0; dc < 4; dc++) {
    const _Float16* zr = zf16 + row * D + dc * 32 + g * 4;
    half4 lo = *(const half4*)zr;
    half4 hi = *(const half4*)(zr + 16);
    half8 f = {lo[0], lo[1], lo[2], lo[3], hi[0], hi[1], hi[2], hi[3]};
    bf[dc] = f;
  }

  unsigned kbest = 0x7FFFFFFFu;
  int kt0 = kb * KT_PER;
  for (int kt = 0; kt < KT_PER; kt++) {
    int ktg = kt0 + kt;
    half8 af[4];
    #pragma unroll
    for (int dc = 0; dc < 4; dc++)
      af[dc] = *(const half8*)(qA + (size_t)((ktg * 4 + dc) * 64 + lane) * 8);
    int4 q4 = *(const int4*)(qid + ktg * 16 + g * 4);
    f32x4 acc = {0.f, 0.f, 0.f, 0.f};
    #pragma unroll
    for (int dc = 0; dc < 4; dc++)
      acc = __builtin_amdgcn_mfma_f32_16x16x32_f16(af[dc], bf[dc], acc, 0, 0, 0);
    #pragma unroll
    for (int r = 0; r < 4; r++) {
      int qv = (r == 0) ? q4.x : (r == 1) ? q4.y : (r == 2) ? q4.z : q4.w;
      float sm = (qv == myid) ? -1.0f : acc[r];
      if (sm == wv) {
        unsigned kk = (unsigned)(ktg * 16 + g * 4 + r);
        kbest = kbest < kk ? kbest : kk;
      }
    }
  }
  unsigned o1 = __shfl_xor(kbest, 16); kbest = kbest < o1 ? kbest : o1;
  unsigned o2 = __shfl_xor(kbest, 32); kbest = kbest < o2 ? kbest : o2;
  if (lane == 0) idxout[row] = (int)(kbest < (K - 1) ? kbest : (K - 1));
}

// Loss: block handles 8 rows (i0..i0+7) for view v. Thread owns columns
// j=tid and j+256 of the 512-wide logits row.
__global__ __launch_bounds__(256) void loss_k(
    const float* __restrict__ q, const float* __restrict__ invn,
    const int* __restrict__ idxout, const float* __restrict__ w,
    float* __restrict__ lpart) {
  int i0 = blockIdx.x * 8;
  int v = blockIdx.y;
  int tid = threadIdx.x;
  __shared__ float nns[8][D];
  __shared__ float rm[8][4], re[8][4], sdlds[8];
  #pragma unroll
  for (int ii = 0; ii < 4; ii++) {
    int i = ii * 2 + (tid >> 7);
    int d = tid & 127;
    int nnidx = idxout[(v ? 0 : B) + i0 + i];
    nns[i][d] = q[(size_t)d * K + nnidx] * invn[nnidx];
  }
  __syncthreads();
  const float* pr = w + (v ? P1_OFF : P0_OFF);
  const float* r0 = pr + tid * D;
  const float* r1 = pr + (tid + 256) * D;
  float a0[8] = {0, 0, 0, 0, 0, 0, 0, 0};
  float a1[8] = {0, 0, 0, 0, 0, 0, 0, 0};
  for (int d = 0; d < D; d += 4) {
    float4 x0 = *(const float4*)(r0 + d);
    float4 x1 = *(const float4*)(r1 + d);
    #pragma unroll
    for (int i = 0; i < 8; i++) {
      float4 n = *(const float4*)&nns[i][d];
      a0[i] = fmaf(x0.x, n.x, a0[i]); a0[i] = fmaf(x0.y, n.y, a0[i]);
      a0[i] = fmaf(x0.z, n.z, a0[i]); a0[i] = fmaf(x0.w, n.w, a0[i]);
      a1[i] = fmaf(x1.x, n.x, a1[i]); a1[i] = fmaf(x1.y, n.y, a1[i]);
      a1[i] = fmaf(x1.z, n.z, a1[i]); a1[i] = fmaf(x1.w, n.w, a1[i]);
    }
  }
  #pragma unroll
  for (int i = 0; i < 8; i++) {
    a0[i] *= (1.0f / TEMP);
    a1[i] *= (1.0f / TEMP);
  }
  #pragma unroll
  for (int i = 0; i < 8; i++) {
    int ig = i0 + i;
    if ((ig & 256) == 0) { if (tid == ig) sdlds[i] = a0[i]; }
    else { if (tid == (ig & 255)) sdlds[i] = a1[i]; }
  }
  int wv = tid >> 6;
  #pragma unroll
  for (int i = 0; i < 8; i++) {
    float m = fmaxf(a0[i], a1[i]);
    #pragma unroll
    for (int o = 32; o; o >>= 1) m = fmaxf(m, __shfl_xor(m, o));
    if ((tid & 63) == 0) rm[i][wv] = m;
  }
  __syncthreads();
  #pragma unroll
  for (int i = 0; i < 8; i++) {
    float m = fmaxf(fmaxf(rm[i][0], rm[i][1]), fmaxf(rm[i][2], rm[i][3]));
    float e = expf(a0[i] - m) + expf(a1[i] - m);
    #pragma unroll
    for (int o = 32; o; o >>= 1) e += __shfl_xor(e, o);
    if ((tid & 63) == 0) re[i][wv] = e;
  }
  __syncthreads();
  if (tid < 8) {
    int i = tid;
    float m = fmaxf(fmaxf(rm[i][0], rm[i][1]), fmaxf(rm[i][2], rm[i][3]));
    float s = re[i][0] + re[i][1] + re[i][2] + re[i][3];
    lpart[v * B + i0 + i] = sdlds[i] - m - logf(s);
  }
}

// Final: loss = -(sum of 1024 partials)/1024 ; also write new_ptr.
__global__ __launch_bounds__(256) void final_k(
    const float* __restrict__ lpart, float* __restrict__ out) {
  int tid = threadIdx.x;
  float s = lpart[tid] + lpart[tid + 256] + lpart[tid + 512] + lpart[tid + 768];
  #pragma unroll
  for (int o = 32; o; o >>= 1) s += __shfl_xor(s, o);
  __shared__ float sm[4];
  if ((tid & 63) == 0) sm[tid >> 6] = s;
  __syncthreads();
  if (tid == 0) {
    float total = sm[0] + sm[1] + sm[2] + sm[3];
    out[0] = -total * (1.0f / 1024.0f);
    out[1 + D * K + K] = 512.0f;
  }
}

extern "C" void kernel_launch(void* const* d_in, const int* in_sizes, int n_in,
                              void* d_out, int out_size, void* d_ws, size_t ws_size,
                              hipStream_t stream) {
  const float* p0 = (const float*)d_in[0];
  const float* p1 = (const float*)d_in[1];
  const float* z0 = (const float*)d_in[2];
  const float* z1 = (const float*)d_in[3];
  const float* q  = (const float*)d_in[4];
  const int* qid  = (const int*)d_in[5];
  const int* ids  = (const int*)d_in[6];
  float* out = (float*)d_out;
  float* w = (float*)d_ws;
  float* invn = w + INVN_OFF;
  _Float16* zf16 = (_Float16*)(w + ZF16_OFF);
  _Float16* qA   = (_Float16*)(w + QA_OFF);
  float* pval = w + PVAL_OFF;
  int* wkb    = (int*)(w + WKB_OFF);
  float* wval = w + WVAL_OFF;
  int* idxout = (int*)(w + IDX_OFF);
  float* lpart = w + LP_OFF;

  rownorm_k<<<2048, 128, 0, stream>>>(p0, p1, z0, z1, w, zf16);
  colq_k<<<K / 128, 256, 0, stream>>>(q, qid, ids, w + Z0_OFF, invn, out, qA);
  nnsearch_k<<<2048, 256, 0, stream>>>(qA, zf16, qid, ids, pval);
  nnreduce_k<<<1024, 256, 0, stream>>>(pval, wkb, wval);
  nnfix_k<<<256, 256, 0, stream>>>(qA, zf16, qid, ids, wkb, wval, idxout);
  dim3 gl(B / 8, 2);
  loss_k<<<gl, 256, 0, stream>>>(q, invn, idxout, w, lpart);
  final_k<<<1, 256, 0, stream>>>(lpart, out);
}

// Round 8
// 136.062 us; speedup vs baseline: 1.1334x; 1.1334x over previous
//
#include <hip/hip_runtime.h>
#include <hip/hip_bf16.h>

typedef _Float16 half8 __attribute__((ext_vector_type(8)));
typedef _Float16 half4 __attribute__((ext_vector_type(4)));
typedef float f32x4 __attribute__((ext_vector_type(4)));

#define B 512
#define D 128
#define K 131072
#define TEMP 0.07f
#define NKB 512      // k-blocks in nnsearch grid
#define KT_PER 16    // 16-wide k-tiles per block (256 cols)

// ws layout in float units
#define INVN_OFF 0
#define Z0_OFF   131072
#define Z1_OFF   196608
#define P0_OFF   262144
#define P1_OFF   327680
#define ZF16_OFF 393216                 // 1024*128 halves = 65536 floats
#define QA_OFF   458752                 // K*D halves = 8388608 floats
#define PVAL_OFF 8847360                // 1024*512 floats
#define WKB_OFF  9371648                // 1024 ints
#define WVAL_OFF 9372672                // 1024 floats
#define IDX_OFF  9373696                // 1024 ints
#define LP_OFF   9374720                // 1024 floats

// Normalize rows of z0, z1, p0, p1 (each B x D) into ws; also z in f16.
__global__ __launch_bounds__(128) void rownorm_k(
    const float* __restrict__ p0, const float* __restrict__ p1,
    const float* __restrict__ z0, const float* __restrict__ z1,
    float* __restrict__ w, _Float16* __restrict__ zf16) {
  int row = blockIdx.x & (B - 1);
  int which = blockIdx.x >> 9;  // 0..3
  const float* src; float* dst;
  switch (which) {
    case 0: src = z0; dst = w + Z0_OFF; break;
    case 1: src = z1; dst = w + Z1_OFF; break;
    case 2: src = p0; dst = w + P0_OFF; break;
    default: src = p1; dst = w + P1_OFF; break;
  }
  int tid = threadIdx.x;
  float v = src[row * D + tid];
  float s = v * v;
  #pragma unroll
  for (int o = 32; o; o >>= 1) s += __shfl_xor(s, o);
  __shared__ float sm[2];
  if ((tid & 63) == 0) sm[tid >> 6] = s;
  __syncthreads();
  float inv = rsqrtf(sm[0] + sm[1]);
  float nv = v * inv;
  dst[row * D + tid] = nv;
  if (which < 2) zf16[(which * B + row) * D + tid] = (_Float16)nv;
}

// Fused, BW-oriented: block owns 128 queue columns.
// Phase 1: float4 loads along k -> column norms (LDS tree reduce).
// Phase 2: L2-hot float4 re-read; scalar new_queue stores (the +1 output
//          offset forbids aligned vector stores); half4 LDS tile writes.
// Phase 3: pack MFMA A-operand fragments (qA) from LDS tile.
__global__ __launch_bounds__(256) void colq_k(
    const float* __restrict__ q, const int* __restrict__ qid,
    const int* __restrict__ ids, const float* __restrict__ w_z0,
    float* __restrict__ invn, float* __restrict__ out,
    _Float16* __restrict__ qA) {
  __shared__ float psum[8][128];
  __shared__ float invs[128];
  __shared__ _Float16 tile[128][136];
  int tid = threadIdx.x;
  int kb = blockIdx.x;           // 0..1023
  int k0 = kb * 128;
  int kc = tid & 31, dg = tid >> 5;
  {
    float4 acc = {0.f, 0.f, 0.f, 0.f};
    for (int i = 0; i < 16; i++) {
      int d = dg * 16 + i;
      float4 v = *(const float4*)(q + (size_t)d * K + k0 + kc * 4);
      acc.x = fmaf(v.x, v.x, acc.x); acc.y = fmaf(v.y, v.y, acc.y);
      acc.z = fmaf(v.z, v.z, acc.z); acc.w = fmaf(v.w, v.w, acc.w);
    }
    *(float4*)&psum[dg][kc * 4] = acc;
  }
  __syncthreads();
  if (tid < 128) {
    float s = 0.f;
    #pragma unroll
    for (int g2 = 0; g2 < 8; g2++) s += psum[g2][tid];
    float inv = rsqrtf(s);
    invs[tid] = inv;
    invn[k0 + tid] = inv;
    int kk = k0 + tid;
    out[1 + (size_t)D * K + kk] = (float)((kk < B) ? ids[kk] : qid[kk]);
  }
  __syncthreads();
  {
    bool zblk = (k0 < B);  // block-uniform: cols come from z0^T
    float4 iv = *(const float4*)&invs[kc * 4];
    for (int i = 0; i < 16; i++) {
      int d = i * 8 + dg;
      float4 v = *(const float4*)(q + (size_t)d * K + k0 + kc * 4);
      float o0 = v.x * iv.x, o1 = v.y * iv.y, o2 = v.z * iv.z, o3 = v.w * iv.w;
      half4 t = {(_Float16)o0, (_Float16)o1, (_Float16)o2, (_Float16)o3};
      *(half4*)&tile[d][kc * 4] = t;
      float* oc = out + 1 + (size_t)d * K + k0 + kc * 4;
      if (zblk) {
        int col = k0 + kc * 4;
        oc[0] = w_z0[(size_t)(col + 0) * D + d];
        oc[1] = w_z0[(size_t)(col + 1) * D + d];
        oc[2] = w_z0[(size_t)(col + 2) * D + d];
        oc[3] = w_z0[(size_t)(col + 3) * D + d];
      } else {
        oc[0] = o0; oc[1] = o1; oc[2] = o2; oc[3] = o3;
      }
    }
  }
  __syncthreads();
  {
    int dc = tid >> 6, l = tid & 63;
    int g = l >> 4, c = l & 15;
    #pragma unroll
    for (int kt = 0; kt < 8; kt++) {
      half8 f;
      #pragma unroll
      for (int i = 0; i < 8; i++) {
        int d = g * 4 + (i & 3) + ((i >> 2) << 4) + dc * 32;
        f[i] = tile[d][kt * 16 + c];
      }
      int ktg = kb * 8 + kt;
      *(half8*)(qA + (size_t)((ktg * 4 + dc) * 64 + l) * 8) = f;
    }
  }
}

#define LOADAF(AF, Q4, KTG) do { \
  _Pragma("unroll") \
  for (int dc = 0; dc < 4; dc++) \
    AF[dc] = *(const half8*)(qA + (size_t)(((KTG) * 4 + dc) * 64 + lane) * 8); \
  Q4 = *(const int4*)(qid + (KTG) * 16 + g * 4); \
} while (0)

// Value-only masked max: 3 VALU ops per element (cmp, cndmask, max).
#define PROCESS(AF, Q4, KTG) do { \
  _Pragma("unroll") \
  for (int nt = 0; nt < 4; nt++) { \
    f32x4 acc = {0.f, 0.f, 0.f, 0.f}; \
    _Pragma("unroll") \
    for (int dc = 0; dc < 4; dc++) \
      acc = __builtin_amdgcn_mfma_f32_16x16x32_f16(AF[dc], bf[nt][dc], acc, 0, 0, 0); \
    _Pragma("unroll") \
    for (int r = 0; r < 4; r++) { \
      int qv_ = (r == 0) ? Q4.x : (r == 1) ? Q4.y : (r == 2) ? Q4.z : Q4.w; \
      float sm_ = (qv_ == myid[nt]) ? -1.0f : acc[r]; \
      best[nt] = fmaxf(best[nt], sm_); \
    } \
  } \
} while (0)

// MFMA NN search pass 1. M = queue index k, N = z-row. Wave owns 64 z-rows
// (B-frags register-resident). XCD-aware decode keeps the 4 rg-blocks of a
// kb on one XCD (qA L2-hot); 2-buffer pipeline keeps VGPR<=~80 so 6
// waves/SIMD provide the TLP that actually hides L2 latency.
__global__ __launch_bounds__(256) void nnsearch_k(
    const _Float16* __restrict__ qA, const _Float16* __restrict__ zf16,
    const int* __restrict__ qid, const int* __restrict__ ids,
    float* __restrict__ pval) {
  int tid = threadIdx.x;
  int flat = blockIdx.x;        // 0..2047
  int cls = flat & 7;           // XCD under round-robin dispatch
  int kb = cls * 64 + (flat >> 5);
  int rg = (flat >> 3) & 3;
  int wave = tid >> 6, lane = tid & 63;
  int g = lane >> 4, c = lane & 15;
  int rowbase = rg * 256 + wave * 64;

  half8 bf[4][4];
  int myid[4];
  #pragma unroll
  for (int nt = 0; nt < 4; nt++) {
    int row = rowbase + nt * 16 + c;
    myid[nt] = ids[row & (B - 1)];
    #pragma unroll
    for (int dc = 0; dc < 4; dc++) {
      const _Float16* zr = zf16 + row * D + dc * 32 + g * 4;
      half4 lo = *(const half4*)zr;
      half4 hi = *(const half4*)(zr + 16);
      half8 f = {lo[0], lo[1], lo[2], lo[3], hi[0], hi[1], hi[2], hi[3]};
      bf[nt][dc] = f;
    }
  }

  float best[4] = {-2.f, -2.f, -2.f, -2.f};
  int kt0 = kb * KT_PER;
  half8 afA[4], afB[4];
  int4 q4A, q4B;
  LOADAF(afA, q4A, kt0);
  for (int kt = 0; kt < KT_PER; kt += 2) {
    LOADAF(afB, q4B, kt0 + kt + 1);
    PROCESS(afA, q4A, kt0 + kt);
    if (kt + 2 < KT_PER) LOADAF(afA, q4A, kt0 + kt + 2);
    PROCESS(afB, q4B, kt0 + kt + 1);
  }

  #pragma unroll
  for (int nt = 0; nt < 4; nt++) {
    float v = best[nt];
    v = fmaxf(v, __shfl_xor(v, 16));
    v = fmaxf(v, __shfl_xor(v, 32));
    if (g == 0) {
      int row = rowbase + nt * 16 + c;
      pval[row * NKB + kb] = v;
    }
  }
}

// Reduce NKB block-maxima per row -> winning block kb (lowest on ties) + its
// exact value. Lossless pack: t=fma(v,.5,3) in [2.5,3.5] has fixed exponent,
// so bits(t)<<9 preserves full mantissa; low 9 bits carry (511-kb).
__global__ __launch_bounds__(256) void nnreduce_k(
    const float* __restrict__ pval, int* __restrict__ wkb,
    float* __restrict__ wval) {
  int row = blockIdx.x;
  int tid = threadIdx.x;
  const float* p = pval + row * NKB;
  float a = p[tid], b = p[tid + 256];
  unsigned pa = (__float_as_uint(fmaf(a, 0.5f, 3.0f)) << 9) | (unsigned)(511 - tid);
  unsigned pb = (__float_as_uint(fmaf(b, 0.5f, 3.0f)) << 9) | (unsigned)(255 - tid);
  unsigned v = pa > pb ? pa : pb;
  #pragma unroll
  for (int o = 32; o; o >>= 1) {
    unsigned ov = __shfl_xor(v, o);
    v = v > ov ? v : ov;
  }
  __shared__ unsigned sv[4];
  if ((tid & 63) == 0) sv[tid >> 6] = v;
  __syncthreads();
  if (tid == 0) {
    #pragma unroll
    for (int wv = 1; wv < 4; wv++) v = v > sv[wv] ? v : sv[wv];
    int kb = 511 - (int)(v & 0x1FFu);
    wkb[row] = kb;
    wval[row] = pval[row * NKB + kb];
  }
}

// Pass 2: exact index recovery inside the winning block. One wave per row;
// the row is replicated into all 16 B-fragment columns, so MFMA reproduces
// bitwise-identical sims; pick the lowest k with sim == wval.
__global__ __launch_bounds__(256) void nnfix_k(
    const _Float16* __restrict__ qA, const _Float16* __restrict__ zf16,
    const int* __restrict__ qid, const int* __restrict__ ids,
    const int* __restrict__ wkb, const float* __restrict__ wval,
    int* __restrict__ idxout) {
  int tid = threadIdx.x;
  int wave = tid >> 6, lane = tid & 63;
  int g = lane >> 4;
  int row = blockIdx.x * 4 + wave;
  int kb = wkb[row];
  float wv = wval[row];
  int myid = ids[row & (B - 1)];

  half8 bf[4];
  #pragma unroll
  for (int dc = 0; dc < 4; dc++) {
    const _Float16* zr = zf16 + row * D + dc * 32 + g * 4;
    half4 lo = *(const half4*)zr;
    half4 hi = *(const half4*)(zr + 16);
    half8 f = {lo[0], lo[1], lo[2], lo[3], hi[0], hi[1], hi[2], hi[3]};
    bf[dc] = f;
  }

  unsigned kbest = 0x7FFFFFFFu;
  int kt0 = kb * KT_PER;
  for (int kt = 0; kt < KT_PER; kt++) {
    int ktg = kt0 + kt;
    half8 af[4];
    #pragma unroll
    for (int dc = 0; dc < 4; dc++)
      af[dc] = *(const half8*)(qA + (size_t)((ktg * 4 + dc) * 64 + lane) * 8);
    int4 q4 = *(const int4*)(qid + ktg * 16 + g * 4);
    f32x4 acc = {0.f, 0.f, 0.f, 0.f};
    #pragma unroll
    for (int dc = 0; dc < 4; dc++)
      acc = __builtin_amdgcn_mfma_f32_16x16x32_f16(af[dc], bf[dc], acc, 0, 0, 0);
    #pragma unroll
    for (int r = 0; r < 4; r++) {
      int qv = (r == 0) ? q4.x : (r == 1) ? q4.y : (r == 2) ? q4.z : q4.w;
      float sm = (qv == myid) ? -1.0f : acc[r];
      if (sm == wv) {
        unsigned kk = (unsigned)(ktg * 16 + g * 4 + r);
        kbest = kbest < kk ? kbest : kk;
      }
    }
  }
  unsigned o1 = __shfl_xor(kbest, 16); kbest = kbest < o1 ? kbest : o1;
  unsigned o2 = __shfl_xor(kbest, 32); kbest = kbest < o2 ? kbest : o2;
  if (lane == 0) idxout[row] = (int)(kbest < (K - 1) ? kbest : (K - 1));
}

// Loss: block handles 8 rows (i0..i0+7) for view v. Thread owns columns
// j=tid and j+256 of the 512-wide logits row.
__global__ __launch_bounds__(256) void loss_k(
    const float* __restrict__ q, const float* __restrict__ invn,
    const int* __restrict__ idxout, const float* __restrict__ w,
    float* __restrict__ lpart) {
  int i0 = blockIdx.x * 8;
  int v = blockIdx.y;
  int tid = threadIdx.x;
  __shared__ float nns[8][D];
  __shared__ float rm[8][4], re[8][4], sdlds[8];
  #pragma unroll
  for (int ii = 0; ii < 4; ii++) {
    int i = ii * 2 + (tid >> 7);
    int d = tid & 127;
    int nnidx = idxout[(v ? 0 : B) + i0 + i];
    nns[i][d] = q[(size_t)d * K + nnidx] * invn[nnidx];
  }
  __syncthreads();
  const float* pr = w + (v ? P1_OFF : P0_OFF);
  const float* r0 = pr + tid * D;
  const float* r1 = pr + (tid + 256) * D;
  float a0[8] = {0, 0, 0, 0, 0, 0, 0, 0};
  float a1[8] = {0, 0, 0, 0, 0, 0, 0, 0};
  for (int d = 0; d < D; d += 4) {
    float4 x0 = *(const float4*)(r0 + d);
    float4 x1 = *(const float4*)(r1 + d);
    #pragma unroll
    for (int i = 0; i < 8; i++) {
      float4 n = *(const float4*)&nns[i][d];
      a0[i] = fmaf(x0.x, n.x, a0[i]); a0[i] = fmaf(x0.y, n.y, a0[i]);
      a0[i] = fmaf(x0.z, n.z, a0[i]); a0[i] = fmaf(x0.w, n.w, a0[i]);
      a1[i] = fmaf(x1.x, n.x, a1[i]); a1[i] = fmaf(x1.y, n.y, a1[i]);
      a1[i] = fmaf(x1.z, n.z, a1[i]); a1[i] = fmaf(x1.w, n.w, a1[i]);
    }
  }
  #pragma unroll
  for (int i = 0; i < 8; i++) {
    a0[i] *= (1.0f / TEMP);
    a1[i] *= (1.0f / TEMP);
  }
  #pragma unroll
  for (int i = 0; i < 8; i++) {
    int ig = i0 + i;
    if ((ig & 256) == 0) { if (tid == ig) sdlds[i] = a0[i]; }
    else { if (tid == (ig & 255)) sdlds[i] = a1[i]; }
  }
  int wv = tid >> 6;
  #pragma unroll
  for (int i = 0; i < 8; i++) {
    float m = fmaxf(a0[i], a1[i]);
    #pragma unroll
    for (int o = 32; o; o >>= 1) m = fmaxf(m, __shfl_xor(m, o));
    if ((tid & 63) == 0) rm[i][wv] = m;
  }
  __syncthreads();
  #pragma unroll
  for (int i = 0; i < 8; i++) {
    float m = fmaxf(fmaxf(rm[i][0], rm[i][1]), fmaxf(rm[i][2], rm[i][3]));
    float e = expf(a0[i] - m) + expf(a1[i] - m);
    #pragma unroll
    for (int o = 32; o; o >>= 1) e += __shfl_xor(e, o);
    if ((tid & 63) == 0) re[i][wv] = e;
  }
  __syncthreads();
  if (tid < 8) {
    int i = tid;
    float m = fmaxf(fmaxf(rm[i][0], rm[i][1]), fmaxf(rm[i][2], rm[i][3]));
    float s = re[i][0] + re[i][1] + re[i][2] + re[i][3];
    lpart[v * B + i0 + i] = sdlds[i] - m - logf(s);
  }
}

// Final: loss = -(sum of 1024 partials)/1024 ; also write new_ptr.
__global__ __launch_bounds__(256) void final_k(
    const float* __restrict__ lpart, float* __restrict__ out) {
  int tid = threadIdx.x;
  float s = lpart[tid] + lpart[tid + 256] + lpart[tid + 512] + lpart[tid + 768];
  #pragma unroll
  for (int o = 32; o; o >>= 1) s += __shfl_xor(s, o);
  __shared__ float sm[4];
  if ((tid & 63) == 0) sm[tid >> 6] = s;
  __syncthreads();
  if (tid == 0) {
    float total = sm[0] + sm[1] + sm[2] + sm[3];
    out[0] = -total * (1.0f / 1024.0f);
    out[1 + D * K + K] = 512.0f;
  }
}

extern "C" void kernel_launch(void* const* d_in, const int* in_sizes, int n_in,
                              void* d_out, int out_size, void* d_ws, size_t ws_size,
                              hipStream_t stream) {
  const float* p0 = (const float*)d_in[0];
  const float* p1 = (const float*)d_in[1];
  const float* z0 = (const float*)d_in[2];
  const float* z1 = (const float*)d_in[3];
  const float* q  = (const float*)d_in[4];
  const int* qid  = (const int*)d_in[5];
  const int* ids  = (const int*)d_in[6];
  float* out = (float*)d_out;
  float* w = (float*)d_ws;
  float* invn = w + INVN_OFF;
  _Float16* zf16 = (_Float16*)(w + ZF16_OFF);
  _Float16* qA   = (_Float16*)(w + QA_OFF);
  float* pval = w + PVAL_OFF;
  int* wkb    = (int*)(w + WKB_OFF);
  float* wval = w + WVAL_OFF;
  int* idxout = (int*)(w + IDX_OFF);
  float* lpart = w + LP_OFF;

  rownorm_k<<<2048, 128, 0, stream>>>(p0, p1, z0, z1, w, zf16);
  colq_k<<<K / 128, 256, 0, stream>>>(q, qid, ids, w + Z0_OFF, invn, out, qA);
  nnsearch_k<<<2048, 256, 0, stream>>>(qA, zf16, qid, ids, pval);
  nnreduce_k<<<1024, 256, 0, stream>>>(pval, wkb, wval);
  nnfix_k<<<256, 256, 0, stream>>>(qA, zf16, qid, ids, wkb, wval, idxout);
  dim3 gl(B / 8, 2);
  loss_k<<<gl, 256, 0, stream>>>(q, invn, idxout, w, lpart);
  final_k<<<1, 256, 0, stream>>>(lpart, out);
}

// Round 9
// 133.493 us; speedup vs baseline: 1.1552x; 1.0192x over previous
//
#include <hip/hip_runtime.h>
#include <hip/hip_bf16.h>

typedef _Float16 half8 __attribute__((ext_vector_type(8)));
typedef _Float16 half4 __attribute__((ext_vector_type(4)));
typedef float f32x4 __attribute__((ext_vector_type(4)));

#define B 512
#define D 128
#define K 131072
#define TEMP 0.07f
#define NKB 512      // k-blocks in nnsearch grid
#define KT_PER 16    // 16-wide k-tiles per block (256 cols)

// ws layout in float units
#define INVN_OFF 0
#define Z0_OFF   131072
#define Z1_OFF   196608
#define P0_OFF   262144
#define P1_OFF   327680
#define ZF16_OFF 393216                 // 1024*128 halves = 65536 floats
#define QA_OFF   458752                 // K*D halves = 8388608 floats
#define PVAL_OFF 8847360                // 1024*512 floats
#define WKB_OFF  9371648                // 1024 ints
#define WVAL_OFF 9372672                // 1024 floats
#define IDX_OFF  9373696                // 1024 ints
#define LP_OFF   9374720                // 1024 floats

// Async global->LDS, 16B per lane; LDS dest is wave-uniform base + lane*16.
__device__ __forceinline__ void gload_lds16(const _Float16* g, _Float16* l) {
  __builtin_amdgcn_global_load_lds(
      (const __attribute__((address_space(1))) unsigned int*)g,
      (__attribute__((address_space(3))) unsigned int*)l, 16, 0, 0);
}

// Normalize rows of z0, z1, p0, p1 (each B x D) into ws; also z in f16.
__global__ __launch_bounds__(128) void rownorm_k(
    const float* __restrict__ p0, const float* __restrict__ p1,
    const float* __restrict__ z0, const float* __restrict__ z1,
    float* __restrict__ w, _Float16* __restrict__ zf16) {
  int row = blockIdx.x & (B - 1);
  int which = blockIdx.x >> 9;  // 0..3
  const float* src; float* dst;
  switch (which) {
    case 0: src = z0; dst = w + Z0_OFF; break;
    case 1: src = z1; dst = w + Z1_OFF; break;
    case 2: src = p0; dst = w + P0_OFF; break;
    default: src = p1; dst = w + P1_OFF; break;
  }
  int tid = threadIdx.x;
  float v = src[row * D + tid];
  float s = v * v;
  #pragma unroll
  for (int o = 32; o; o >>= 1) s += __shfl_xor(s, o);
  __shared__ float sm[2];
  if ((tid & 63) == 0) sm[tid >> 6] = s;
  __syncthreads();
  float inv = rsqrtf(sm[0] + sm[1]);
  float nv = v * inv;
  dst[row * D + tid] = nv;
  if (which < 2) zf16[(which * B + row) * D + tid] = (_Float16)nv;
}

// Fused, BW-oriented: block owns 128 queue columns.
__global__ __launch_bounds__(256) void colq_k(
    const float* __restrict__ q, const int* __restrict__ qid,
    const int* __restrict__ ids, const float* __restrict__ w_z0,
    float* __restrict__ invn, float* __restrict__ out,
    _Float16* __restrict__ qA) {
  __shared__ float psum[8][128];
  __shared__ float invs[128];
  __shared__ _Float16 tile[128][136];
  int tid = threadIdx.x;
  int kb = blockIdx.x;           // 0..1023
  int k0 = kb * 128;
  int kc = tid & 31, dg = tid >> 5;
  {
    float4 acc = {0.f, 0.f, 0.f, 0.f};
    for (int i = 0; i < 16; i++) {
      int d = dg * 16 + i;
      float4 v = *(const float4*)(q + (size_t)d * K + k0 + kc * 4);
      acc.x = fmaf(v.x, v.x, acc.x); acc.y = fmaf(v.y, v.y, acc.y);
      acc.z = fmaf(v.z, v.z, acc.z); acc.w = fmaf(v.w, v.w, acc.w);
    }
    *(float4*)&psum[dg][kc * 4] = acc;
  }
  __syncthreads();
  if (tid < 128) {
    float s = 0.f;
    #pragma unroll
    for (int g2 = 0; g2 < 8; g2++) s += psum[g2][tid];
    float inv = rsqrtf(s);
    invs[tid] = inv;
    invn[k0 + tid] = inv;
    int kk = k0 + tid;
    out[1 + (size_t)D * K + kk] = (float)((kk < B) ? ids[kk] : qid[kk]);
  }
  __syncthreads();
  {
    bool zblk = (k0 < B);  // block-uniform: cols come from z0^T
    float4 iv = *(const float4*)&invs[kc * 4];
    for (int i = 0; i < 16; i++) {
      int d = i * 8 + dg;
      float4 v = *(const float4*)(q + (size_t)d * K + k0 + kc * 4);
      float o0 = v.x * iv.x, o1 = v.y * iv.y, o2 = v.z * iv.z, o3 = v.w * iv.w;
      half4 t = {(_Float16)o0, (_Float16)o1, (_Float16)o2, (_Float16)o3};
      *(half4*)&tile[d][kc * 4] = t;
      float* oc = out + 1 + (size_t)d * K + k0 + kc * 4;
      if (zblk) {
        int col = k0 + kc * 4;
        oc[0] = w_z0[(size_t)(col + 0) * D + d];
        oc[1] = w_z0[(size_t)(col + 1) * D + d];
        oc[2] = w_z0[(size_t)(col + 2) * D + d];
        oc[3] = w_z0[(size_t)(col + 3) * D + d];
      } else {
        oc[0] = o0; oc[1] = o1; oc[2] = o2; oc[3] = o3;
      }
    }
  }
  __syncthreads();
  {
    int dc = tid >> 6, l = tid & 63;
    int g = l >> 4, c = l & 15;
    #pragma unroll
    for (int kt = 0; kt < 8; kt++) {
      half8 f;
      #pragma unroll
      for (int i = 0; i < 8; i++) {
        int d = g * 4 + (i & 3) + ((i >> 2) << 4) + dc * 32;
        f[i] = tile[d][kt * 16 + c];
      }
      int ktg = kb * 8 + kt;
      *(half8*)(qA + (size_t)((ktg * 4 + dc) * 64 + l) * 8) = f;
    }
  }
}

// Value-only masked max: 3 VALU ops per element (cmp, cndmask, max).
#define PROCESS(AF, Q4, KTG) do { \
  _Pragma("unroll") \
  for (int nt = 0; nt < 4; nt++) { \
    f32x4 acc = {0.f, 0.f, 0.f, 0.f}; \
    _Pragma("unroll") \
    for (int dc = 0; dc < 4; dc++) \
      acc = __builtin_amdgcn_mfma_f32_16x16x32_f16(AF[dc], bf[nt][dc], acc, 0, 0, 0); \
    _Pragma("unroll") \
    for (int r = 0; r < 4; r++) { \
      int qv_ = (r == 0) ? Q4.x : (r == 1) ? Q4.y : (r == 2) ? Q4.z : Q4.w; \
      float sm_ = (qv_ == myid[nt]) ? -1.0f : acc[r]; \
      best[nt] = fmaxf(best[nt], sm_); \
    } \
  } \
} while (0)

// MFMA NN search pass 1. M = queue index k, N = z-row. Wave owns 64 z-rows
// (B-frags register-resident). Per-block LDS staging of the shared qA tile:
// each wave global_load_lds's its quarter (1KB) of the 4KB kt-tile; double
// buffer, counted vmcnt (never 0 mid-loop), raw barriers + sched_barrier
// pins (rule #18). qid comes from a 1KB LDS copy (no global loads in loop).
__global__ __launch_bounds__(256) void nnsearch_k(
    const _Float16* __restrict__ qA, const _Float16* __restrict__ zf16,
    const int* __restrict__ qid, const int* __restrict__ ids,
    float* __restrict__ pval) {
  __shared__ __align__(16) _Float16 qtile[2][2048];
  __shared__ __align__(16) int qid_lds[256];
  int tid = threadIdx.x;
  int flat = blockIdx.x;        // 0..2047
  int cls = flat & 7;           // XCD under round-robin dispatch
  int kb = cls * 64 + (flat >> 5);
  int rg = (flat >> 3) & 3;
  int wave = tid >> 6, lane = tid & 63;
  int g = lane >> 4, c = lane & 15;
  int rowbase = rg * 256 + wave * 64;
  int kt0 = kb * KT_PER;

  // prologue: stage tiles 0,1 + qid copy (drained by __syncthreads below)
  gload_lds16(qA + (size_t)(((kt0 + 0) * 4 + wave) * 64 + lane) * 8,
              &qtile[0][wave * 512]);
  gload_lds16(qA + (size_t)(((kt0 + 1) * 4 + wave) * 64 + lane) * 8,
              &qtile[1][wave * 512]);
  qid_lds[tid] = qid[kb * 256 + tid];

  half8 bf[4][4];
  int myid[4];
  #pragma unroll
  for (int nt = 0; nt < 4; nt++) {
    int row = rowbase + nt * 16 + c;
    myid[nt] = ids[row & (B - 1)];
    #pragma unroll
    for (int dc = 0; dc < 4; dc++) {
      const _Float16* zr = zf16 + row * D + dc * 32 + g * 4;
      half4 lo = *(const half4*)zr;
      half4 hi = *(const half4*)(zr + 16);
      half8 f = {lo[0], lo[1], lo[2], lo[3], hi[0], hi[1], hi[2], hi[3]};
      bf[nt][dc] = f;
    }
  }
  __syncthreads();   // drains prologue stages + qid_lds write

  float best[4] = {-2.f, -2.f, -2.f, -2.f};
  for (int kt = 0; kt < KT_PER; kt++) {
    int cur = kt & 1;
    half8 af[4];
    #pragma unroll
    for (int dc = 0; dc < 4; dc++)
      af[dc] = *(const half8*)&qtile[cur][dc * 512 + lane * 8];
    int4 q4 = *(const int4*)&qid_lds[kt * 16 + g * 4];
    // reads retired -> all waves aligned -> safe to restage buf[cur]
    asm volatile("s_waitcnt lgkmcnt(0)" ::: "memory");
    __builtin_amdgcn_sched_barrier(0);
    __builtin_amdgcn_s_barrier();
    __builtin_amdgcn_sched_barrier(0);
    if (kt + 2 < KT_PER)
      gload_lds16(qA + (size_t)(((kt0 + kt + 2) * 4 + wave) * 64 + lane) * 8,
                  &qtile[cur][wave * 512]);
    PROCESS(af, q4, kt0 + kt);
    if (kt + 1 < KT_PER) {
      // counted wait: ensure own stage(kt+1) done (one younger may fly)
      if (kt + 2 < KT_PER) asm volatile("s_waitcnt vmcnt(1)" ::: "memory");
      else                 asm volatile("s_waitcnt vmcnt(0)" ::: "memory");
      __builtin_amdgcn_sched_barrier(0);
      __builtin_amdgcn_s_barrier();   // all waves' stage(kt+1) done
      __builtin_amdgcn_sched_barrier(0);
    }
  }

  #pragma unroll
  for (int nt = 0; nt < 4; nt++) {
    float v = best[nt];
    v = fmaxf(v, __shfl_xor(v, 16));
    v = fmaxf(v, __shfl_xor(v, 32));
    if (g == 0) {
      int row = rowbase + nt * 16 + c;
      pval[row * NKB + kb] = v;
    }
  }
}

// Reduce NKB block-maxima per row -> winning block kb (lowest on ties) + its
// exact value. Lossless pack: t=fma(v,.5,3) in [2.5,3.5] has fixed exponent,
// so bits(t)<<9 preserves full mantissa; low 9 bits carry (511-kb).
__global__ __launch_bounds__(256) void nnreduce_k(
    const float* __restrict__ pval, int* __restrict__ wkb,
    float* __restrict__ wval) {
  int row = blockIdx.x;
  int tid = threadIdx.x;
  const float* p = pval + row * NKB;
  float a = p[tid], b = p[tid + 256];
  unsigned pa = (__float_as_uint(fmaf(a, 0.5f, 3.0f)) << 9) | (unsigned)(511 - tid);
  unsigned pb = (__float_as_uint(fmaf(b, 0.5f, 3.0f)) << 9) | (unsigned)(255 - tid);
  unsigned v = pa > pb ? pa : pb;
  #pragma unroll
  for (int o = 32; o; o >>= 1) {
    unsigned ov = __shfl_xor(v, o);
    v = v > ov ? v : ov;
  }
  __shared__ unsigned sv[4];
  if ((tid & 63) == 0) sv[tid >> 6] = v;
  __syncthreads();
  if (tid == 0) {
    #pragma unroll
    for (int wv = 1; wv < 4; wv++) v = v > sv[wv] ? v : sv[wv];
    int kb = 511 - (int)(v & 0x1FFu);
    wkb[row] = kb;
    wval[row] = pval[row * NKB + kb];
  }
}

// Pass 2: exact index recovery inside the winning block. One wave per row;
// the row is replicated into all 16 B-fragment columns, so MFMA reproduces
// bitwise-identical sims; pick the lowest k with sim == wval.
__global__ __launch_bounds__(256) void nnfix_k(
    const _Float16* __restrict__ qA, const _Float16* __restrict__ zf16,
    const int* __restrict__ qid, const int* __restrict__ ids,
    const int* __restrict__ wkb, const float* __restrict__ wval,
    int* __restrict__ idxout) {
  int tid = threadIdx.x;
  int wave = tid >> 6, lane = tid & 63;
  int g = lane >> 4;
  int row = blockIdx.x * 4 + wave;
  int kb = wkb[row];
  float wv = wval[row];
  int myid = ids[row & (B - 1)];

  half8 bf[4];
  #pragma unroll
  for (int dc = 0; dc < 4; dc++) {
    const _Float16* zr = zf16 + row * D + dc * 32 + g * 4;
    half4 lo = *(const half4*)zr;
    half4 hi = *(const half4*)(zr + 16);
    half8 f = {lo[0], lo[1], lo[2], lo[3], hi[0], hi[1], hi[2], hi[3]};
    bf[dc] = f;
  }

  unsigned kbest = 0x7FFFFFFFu;
  int kt0 = kb * KT_PER;
  for (int kt = 0; kt < KT_PER; kt++) {
    int ktg = kt0 + kt;
    half8 af[4];
    #pragma unroll
    for (int dc = 0; dc < 4; dc++)
      af[dc] = *(const half8*)(qA + (size_t)((ktg * 4 + dc) * 64 + lane) * 8);
    int4 q4 = *(const int4*)(qid + ktg * 16 + g * 4);
    f32x4 acc = {0.f, 0.f, 0.f, 0.f};
    #pragma unroll
    for (int dc = 0; dc < 4; dc++)
      acc = __builtin_amdgcn_mfma_f32_16x16x32_f16(af[dc], bf[dc], acc, 0, 0, 0);
    #pragma unroll
    for (int r = 0; r < 4; r++) {
      int qv = (r == 0) ? q4.x : (r == 1) ? q4.y : (r == 2) ? q4.z : q4.w;
      float sm = (qv == myid) ? -1.0f : acc[r];
      if (sm == wv) {
        unsigned kk = (unsigned)(ktg * 16 + g * 4 + r);
        kbest = kbest < kk ? kbest : kk;
      }
    }
  }
  unsigned o1 = __shfl_xor(kbest, 16); kbest = kbest < o1 ? kbest : o1;
  unsigned o2 = __shfl_xor(kbest, 32); kbest = kbest < o2 ? kbest : o2;
  if (lane == 0) idxout[row] = (int)(kbest < (K - 1) ? kbest : (K - 1));
}

// Loss: block handles 8 rows (i0..i0+7) for view v. Thread owns columns
// j=tid and j+256 of the 512-wide logits row.
__global__ __launch_bounds__(256) void loss_k(
    const float* __restrict__ q, const float* __restrict__ invn,
    const int* __restrict__ idxout, const float* __restrict__ w,
    float* __restrict__ lpart) {
  int i0 = blockIdx.x * 8;
  int v = blockIdx.y;
  int tid = threadIdx.x;
  __shared__ float nns[8][D];
  __shared__ float rm[8][4], re[8][4], sdlds[8];
  #pragma unroll
  for (int ii = 0; ii < 4; ii++) {
    int i = ii * 2 + (tid >> 7);
    int d = tid & 127;
    int nnidx = idxout[(v ? 0 : B) + i0 + i];
    nns[i][d] = q[(size_t)d * K + nnidx] * invn[nnidx];
  }
  __syncthreads();
  const float* pr = w + (v ? P1_OFF : P0_OFF);
  const float* r0 = pr + tid * D;
  const float* r1 = pr + (tid + 256) * D;
  float a0[8] = {0, 0, 0, 0, 0, 0, 0, 0};
  float a1[8] = {0, 0, 0, 0, 0, 0, 0, 0};
  for (int d = 0; d < D; d += 4) {
    float4 x0 = *(const float4*)(r0 + d);
    float4 x1 = *(const float4*)(r1 + d);
    #pragma unroll
    for (int i = 0; i < 8; i++) {
      float4 n = *(const float4*)&nns[i][d];
      a0[i] = fmaf(x0.x, n.x, a0[i]); a0[i] = fmaf(x0.y, n.y, a0[i]);
      a0[i] = fmaf(x0.z, n.z, a0[i]); a0[i] = fmaf(x0.w, n.w, a0[i]);
      a1[i] = fmaf(x1.x, n.x, a1[i]); a1[i] = fmaf(x1.y, n.y, a1[i]);
      a1[i] = fmaf(x1.z, n.z, a1[i]); a1[i] = fmaf(x1.w, n.w, a1[i]);
    }
  }
  #pragma unroll
  for (int i = 0; i < 8; i++) {
    a0[i] *= (1.0f / TEMP);
    a1[i] *= (1.0f / TEMP);
  }
  #pragma unroll
  for (int i = 0; i < 8; i++) {
    int ig = i0 + i;
    if ((ig & 256) == 0) { if (tid == ig) sdlds[i] = a0[i]; }
    else { if (tid == (ig & 255)) sdlds[i] = a1[i]; }
  }
  int wv = tid >> 6;
  #pragma unroll
  for (int i = 0; i < 8; i++) {
    float m = fmaxf(a0[i], a1[i]);
    #pragma unroll
    for (int o = 32; o; o >>= 1) m = fmaxf(m, __shfl_xor(m, o));
    if ((tid & 63) == 0) rm[i][wv] = m;
  }
  __syncthreads();
  #pragma unroll
  for (int i = 0; i < 8; i++) {
    float m = fmaxf(fmaxf(rm[i][0], rm[i][1]), fmaxf(rm[i][2], rm[i][3]));
    float e = expf(a0[i] - m) + expf(a1[i] - m);
    #pragma unroll
    for (int o = 32; o; o >>= 1) e += __shfl_xor(e, o);
    if ((tid & 63) == 0) re[i][wv] = e;
  }
  __syncthreads();
  if (tid < 8) {
    int i = tid;
    float m = fmaxf(fmaxf(rm[i][0], rm[i][1]), fmaxf(rm[i][2], rm[i][3]));
    float s = re[i][0] + re[i][1] + re[i][2] + re[i][3];
    lpart[v * B + i0 + i] = sdlds[i] - m - logf(s);
  }
}

// Final: loss = -(sum of 1024 partials)/1024 ; also write new_ptr.
__global__ __launch_bounds__(256) void final_k(
    const float* __restrict__ lpart, float* __restrict__ out) {
  int tid = threadIdx.x;
  float s = lpart[tid] + lpart[tid + 256] + lpart[tid + 512] + lpart[tid + 768];
  #pragma unroll
  for (int o = 32; o; o >>= 1) s += __shfl_xor(s, o);
  __shared__ float sm[4];
  if ((tid & 63) == 0) sm[tid >> 6] = s;
  __syncthreads();
  if (tid == 0) {
    float total = sm[0] + sm[1] + sm[2] + sm[3];
    out[0] = -total * (1.0f / 1024.0f);
    out[1 + D * K + K] = 512.0f;
  }
}

extern "C" void kernel_launch(void* const* d_in, const int* in_sizes, int n_in,
                              void* d_out, int out_size, void* d_ws, size_t ws_size,
                              hipStream_t stream) {
  const float* p0 = (const float*)d_in[0];
  const float* p1 = (const float*)d_in[1];
  const float* z0 = (const float*)d_in[2];
  const float* z1 = (const float*)d_in[3];
  const float* q  = (const float*)d_in[4];
  const int* qid  = (const int*)d_in[5];
  const int* ids  = (const int*)d_in[6];
  float* out = (float*)d_out;
  float* w = (float*)d_ws;
  float* invn = w + INVN_OFF;
  _Float16* zf16 = (_Float16*)(w + ZF16_OFF);
  _Float16* qA   = (_Float16*)(w + QA_OFF);
  float* pval = w + PVAL_OFF;
  int* wkb    = (int*)(w + WKB_OFF);
  float* wval = w + WVAL_OFF;
  int* idxout = (int*)(w + IDX_OFF);
  float* lpart = w + LP_OFF;

  rownorm_k<<<2048, 128, 0, stream>>>(p0, p1, z0, z1, w, zf16);
  colq_k<<<K / 128, 256, 0, stream>>>(q, qid, ids, w + Z0_OFF, invn, out, qA);
  nnsearch_k<<<2048, 256, 0, stream>>>(qA, zf16, qid, ids, pval);
  nnreduce_k<<<1024, 256, 0, stream>>>(pval, wkb, wval);
  nnfix_k<<<256, 256, 0, stream>>>(qA, zf16, qid, ids, wkb, wval, idxout);
  dim3 gl(B / 8, 2);
  loss_k<<<gl, 256, 0, stream>>>(q, invn, idxout, w, lpart);
  final_k<<<1, 256, 0, stream>>>(lpart, out);
}

// Round 10
// 127.545 us; speedup vs baseline: 1.2091x; 1.0466x over previous
//
#include <hip/hip_runtime.h>
#include <hip/hip_bf16.h>

typedef _Float16 half8 __attribute__((ext_vector_type(8)));
typedef _Float16 half4 __attribute__((ext_vector_type(4)));
typedef float f32x4 __attribute__((ext_vector_type(4)));

#define B 512
#define D 128
#define K 131072
#define TEMP 0.07f
#define NKB 256      // k-blocks in nnsearch grid
#define KT_PER 32    // 16-wide k-tiles per block (512 cols)
#define NSS 16       // superstages (2 kt each)

// ws layout in float units
#define INVN_OFF 0
#define Z0_OFF   131072
#define Z1_OFF   196608
#define P0_OFF   262144
#define P1_OFF   327680
#define ZF16_OFF 393216                 // 1024*128 halves = 65536 floats
#define QA_OFF   458752                 // K*D halves = 8388608 floats
#define PVAL_OFF 8847360                // 1024*256 floats
#define WKB_OFF  9371648                // 1024 ints
#define WVAL_OFF 9372672                // 1024 floats
#define IDX_OFF  9373696                // 1024 ints
#define LP_OFF   9374720                // 1024 floats

// Async global->LDS, 16B per lane; LDS dest is wave-uniform base + lane*16.
__device__ __forceinline__ void gload_lds16(const _Float16* g, _Float16* l) {
  __builtin_amdgcn_global_load_lds(
      (const __attribute__((address_space(1))) unsigned int*)g,
      (__attribute__((address_space(3))) unsigned int*)l, 16, 0, 0);
}

// Normalize rows of z0, z1, p0, p1 (each B x D) into ws; also z in f16.
__global__ __launch_bounds__(128) void rownorm_k(
    const float* __restrict__ p0, const float* __restrict__ p1,
    const float* __restrict__ z0, const float* __restrict__ z1,
    float* __restrict__ w, _Float16* __restrict__ zf16) {
  int row = blockIdx.x & (B - 1);
  int which = blockIdx.x >> 9;  // 0..3
  const float* src; float* dst;
  switch (which) {
    case 0: src = z0; dst = w + Z0_OFF; break;
    case 1: src = z1; dst = w + Z1_OFF; break;
    case 2: src = p0; dst = w + P0_OFF; break;
    default: src = p1; dst = w + P1_OFF; break;
  }
  int tid = threadIdx.x;
  float v = src[row * D + tid];
  float s = v * v;
  #pragma unroll
  for (int o = 32; o; o >>= 1) s += __shfl_xor(s, o);
  __shared__ float sm[2];
  if ((tid & 63) == 0) sm[tid >> 6] = s;
  __syncthreads();
  float inv = rsqrtf(sm[0] + sm[1]);
  float nv = v * inv;
  dst[row * D + tid] = nv;
  if (which < 2) zf16[(which * B + row) * D + tid] = (_Float16)nv;
}

// Fused, BW-oriented: block owns 128 queue columns.
__global__ __launch_bounds__(256) void colq_k(
    const float* __restrict__ q, const int* __restrict__ qid,
    const int* __restrict__ ids, const float* __restrict__ w_z0,
    float* __restrict__ invn, float* __restrict__ out,
    _Float16* __restrict__ qA) {
  __shared__ float psum[8][128];
  __shared__ float invs[128];
  __shared__ _Float16 tile[128][136];
  int tid = threadIdx.x;
  int kb = blockIdx.x;           // 0..1023
  int k0 = kb * 128;
  int kc = tid & 31, dg = tid >> 5;
  {
    float4 acc = {0.f, 0.f, 0.f, 0.f};
    for (int i = 0; i < 16; i++) {
      int d = dg * 16 + i;
      float4 v = *(const float4*)(q + (size_t)d * K + k0 + kc * 4);
      acc.x = fmaf(v.x, v.x, acc.x); acc.y = fmaf(v.y, v.y, acc.y);
      acc.z = fmaf(v.z, v.z, acc.z); acc.w = fmaf(v.w, v.w, acc.w);
    }
    *(float4*)&psum[dg][kc * 4] = acc;
  }
  __syncthreads();
  if (tid < 128) {
    float s = 0.f;
    #pragma unroll
    for (int g2 = 0; g2 < 8; g2++) s += psum[g2][tid];
    float inv = rsqrtf(s);
    invs[tid] = inv;
    invn[k0 + tid] = inv;
    int kk = k0 + tid;
    out[1 + (size_t)D * K + kk] = (float)((kk < B) ? ids[kk] : qid[kk]);
  }
  __syncthreads();
  {
    bool zblk = (k0 < B);  // block-uniform: cols come from z0^T
    float4 iv = *(const float4*)&invs[kc * 4];
    for (int i = 0; i < 16; i++) {
      int d = i * 8 + dg;
      float4 v = *(const float4*)(q + (size_t)d * K + k0 + kc * 4);
      float o0 = v.x * iv.x, o1 = v.y * iv.y, o2 = v.z * iv.z, o3 = v.w * iv.w;
      half4 t = {(_Float16)o0, (_Float16)o1, (_Float16)o2, (_Float16)o3};
      *(half4*)&tile[d][kc * 4] = t;
      float* oc = out + 1 + (size_t)d * K + k0 + kc * 4;
      if (zblk) {
        int col = k0 + kc * 4;
        oc[0] = w_z0[(size_t)(col + 0) * D + d];
        oc[1] = w_z0[(size_t)(col + 1) * D + d];
        oc[2] = w_z0[(size_t)(col + 2) * D + d];
        oc[3] = w_z0[(size_t)(col + 3) * D + d];
      } else {
        oc[0] = o0; oc[1] = o1; oc[2] = o2; oc[3] = o3;
      }
    }
  }
  __syncthreads();
  {
    int dc = tid >> 6, l = tid & 63;
    int g = l >> 4, c = l & 15;
    #pragma unroll
    for (int kt = 0; kt < 8; kt++) {
      half8 f;
      #pragma unroll
      for (int i = 0; i < 8; i++) {
        int d = g * 4 + (i & 3) + ((i >> 2) << 4) + dc * 32;
        f[i] = tile[d][kt * 16 + c];
      }
      int ktg = kb * 8 + kt;
      *(half8*)(qA + (size_t)((ktg * 4 + dc) * 64 + l) * 8) = f;
    }
  }
}

// Value-only masked max: 3 VALU ops per element (cmp, cndmask, max).
#define PROCESS(AF, Q4) do { \
  _Pragma("unroll") \
  for (int nt = 0; nt < 4; nt++) { \
    f32x4 acc = {0.f, 0.f, 0.f, 0.f}; \
    _Pragma("unroll") \
    for (int dc = 0; dc < 4; dc++) \
      acc = __builtin_amdgcn_mfma_f32_16x16x32_f16(AF[dc], bf[nt][dc], acc, 0, 0, 0); \
    _Pragma("unroll") \
    for (int r = 0; r < 4; r++) { \
      int qv_ = (r == 0) ? Q4.x : (r == 1) ? Q4.y : (r == 2) ? Q4.z : Q4.w; \
      float sm_ = (qv_ == myid[nt]) ? -1.0f : acc[r]; \
      best[nt] = fmaxf(best[nt], sm_); \
    } \
  } \
} while (0)

// MFMA NN search pass 1. M = queue index k, N = z-row. Wave owns 64 z-rows
// (B-frags register-resident). 3-buffer LDS ring, superstage = 2 kt (8KB),
// ONE barrier per superstage, counted vmcnt(2) mid-loop (never 0). Ledger:
//  - read buf[s%3] needs stage(s) done by all waves: end-of-(s-1) vmcnt(2)
//    retires stage(s) per-wave, barrier aligns the block.
//  - restage buf[(s+2)%3] overwrites superstage s-1's data, whose reads
//    retired before the end-of-(s-1) barrier (lgkmcnt(0) precedes it).
__global__ __launch_bounds__(256) void nnsearch_k(
    const _Float16* __restrict__ qA, const _Float16* __restrict__ zf16,
    const int* __restrict__ qid, const int* __restrict__ ids,
    float* __restrict__ pval) {
  __shared__ __align__(16) _Float16 qtile[3][2][2048];
  __shared__ __align__(16) int qid_lds[512];
  int tid = threadIdx.x;
  int flat = blockIdx.x;        // 0..1023
  int cls = flat & 7;           // XCD under round-robin dispatch
  int kb = cls * 32 + (flat >> 5);
  int rg = (flat >> 3) & 3;
  int wave = tid >> 6, lane = tid & 63;
  int g = lane >> 4, c = lane & 15;
  int rowbase = rg * 256 + wave * 64;
  int kt0 = kb * KT_PER;

  // prologue: stage superstages 0,1 + qid copy (drained by __syncthreads)
  #pragma unroll
  for (int j = 0; j < 2; j++)
    gload_lds16(qA + (size_t)(((kt0 + j) * 4 + wave) * 64 + lane) * 8,
                &qtile[0][j][wave * 512]);
  #pragma unroll
  for (int j = 0; j < 2; j++)
    gload_lds16(qA + (size_t)(((kt0 + 2 + j) * 4 + wave) * 64 + lane) * 8,
                &qtile[1][j][wave * 512]);
  qid_lds[tid] = qid[kb * 512 + tid];
  qid_lds[tid + 256] = qid[kb * 512 + tid + 256];

  half8 bf[4][4];
  int myid[4];
  #pragma unroll
  for (int nt = 0; nt < 4; nt++) {
    int row = rowbase + nt * 16 + c;
    myid[nt] = ids[row & (B - 1)];
    #pragma unroll
    for (int dc = 0; dc < 4; dc++) {
      const _Float16* zr = zf16 + row * D + dc * 32 + g * 4;
      half4 lo = *(const half4*)zr;
      half4 hi = *(const half4*)(zr + 16);
      half8 f = {lo[0], lo[1], lo[2], lo[3], hi[0], hi[1], hi[2], hi[3]};
      bf[nt][dc] = f;
    }
  }
  __syncthreads();   // drains prologue stages + qid_lds writes

  float best[4] = {-2.f, -2.f, -2.f, -2.f};
  int cur = 0;
  for (int s = 0; s < NSS; s++) {
    half8 af0[4], af1[4];
    #pragma unroll
    for (int dc = 0; dc < 4; dc++)
      af0[dc] = *(const half8*)&qtile[cur][0][dc * 512 + lane * 8];
    #pragma unroll
    for (int dc = 0; dc < 4; dc++)
      af1[dc] = *(const half8*)&qtile[cur][1][dc * 512 + lane * 8];
    int4 q4a = *(const int4*)&qid_lds[(s * 2 + 0) * 16 + g * 4];
    int4 q4b = *(const int4*)&qid_lds[(s * 2 + 1) * 16 + g * 4];
    if (s + 2 < NSS) {
      int nbuf = cur + 2; if (nbuf >= 3) nbuf -= 3;
      #pragma unroll
      for (int j = 0; j < 2; j++)
        gload_lds16(qA + (size_t)(((kt0 + (s + 2) * 2 + j) * 4 + wave) * 64 + lane) * 8,
                    &qtile[nbuf][j][wave * 512]);
    }
    PROCESS(af0, q4a);
    PROCESS(af1, q4b);
    if (s < NSS - 1) {
      asm volatile("s_waitcnt lgkmcnt(0)" ::: "memory");
      if (s + 2 < NSS) asm volatile("s_waitcnt vmcnt(2)" ::: "memory");
      else             asm volatile("s_waitcnt vmcnt(0)" ::: "memory");
      __builtin_amdgcn_sched_barrier(0);
      __builtin_amdgcn_s_barrier();
      __builtin_amdgcn_sched_barrier(0);
    }
    cur += 1; if (cur >= 3) cur -= 3;
  }

  #pragma unroll
  for (int nt = 0; nt < 4; nt++) {
    float v = best[nt];
    v = fmaxf(v, __shfl_xor(v, 16));
    v = fmaxf(v, __shfl_xor(v, 32));
    if (g == 0) {
      int row = rowbase + nt * 16 + c;
      pval[row * NKB + kb] = v;
    }
  }
}

// Reduce NKB block-maxima per row -> winning block kb (lowest on ties) + its
// exact value. Lossless pack: t=fma(v,.5,3) in [2.5,3.5] has fixed exponent,
// so bits(t)<<9 preserves full mantissa; low 9 bits carry (NKB-1-kb).
__global__ __launch_bounds__(256) void nnreduce_k(
    const float* __restrict__ pval, int* __restrict__ wkb,
    float* __restrict__ wval) {
  int row = blockIdx.x;
  int tid = threadIdx.x;
  const float* p = pval + row * NKB;
  float a = p[tid];
  unsigned v = (__float_as_uint(fmaf(a, 0.5f, 3.0f)) << 9) | (unsigned)(NKB - 1 - tid);
  #pragma unroll
  for (int o = 32; o; o >>= 1) {
    unsigned ov = __shfl_xor(v, o);
    v = v > ov ? v : ov;
  }
  __shared__ unsigned sv[4];
  if ((tid & 63) == 0) sv[tid >> 6] = v;
  __syncthreads();
  if (tid == 0) {
    #pragma unroll
    for (int wv = 1; wv < 4; wv++) v = v > sv[wv] ? v : sv[wv];
    int kb = (NKB - 1) - (int)(v & 0x1FFu);
    wkb[row] = kb;
    wval[row] = pval[row * NKB + kb];
  }
}

// Pass 2: exact index recovery inside the winning block. One wave per row;
// the row is replicated into all 16 B-fragment columns, so MFMA reproduces
// bitwise-identical sims; pick the lowest k with sim == wval.
__global__ __launch_bounds__(256) void nnfix_k(
    const _Float16* __restrict__ qA, const _Float16* __restrict__ zf16,
    const int* __restrict__ qid, const int* __restrict__ ids,
    const int* __restrict__ wkb, const float* __restrict__ wval,
    int* __restrict__ idxout) {
  int tid = threadIdx.x;
  int wave = tid >> 6, lane = tid & 63;
  int g = lane >> 4;
  int row = blockIdx.x * 4 + wave;
  int kb = wkb[row];
  float wv = wval[row];
  int myid = ids[row & (B - 1)];

  half8 bf[4];
  #pragma unroll
  for (int dc = 0; dc < 4; dc++) {
    const _Float16* zr = zf16 + row * D + dc * 32 + g * 4;
    half4 lo = *(const half4*)zr;
    half4 hi = *(const half4*)(zr + 16);
    half8 f = {lo[0], lo[1], lo[2], lo[3], hi[0], hi[1], hi[2], hi[3]};
    bf[dc] = f;
  }

  unsigned kbest = 0x7FFFFFFFu;
  int kt0 = kb * KT_PER;
  for (int kt = 0; kt < KT_PER; kt++) {
    int ktg = kt0 + kt;
    half8 af[4];
    #pragma unroll
    for (int dc = 0; dc < 4; dc++)
      af[dc] = *(const half8*)(qA + (size_t)((ktg * 4 + dc) * 64 + lane) * 8);
    int4 q4 = *(const int4*)(qid + ktg * 16 + g * 4);
    f32x4 acc = {0.f, 0.f, 0.f, 0.f};
    #pragma unroll
    for (int dc = 0; dc < 4; dc++)
      acc = __builtin_amdgcn_mfma_f32_16x16x32_f16(af[dc], bf[dc], acc, 0, 0, 0);
    #pragma unroll
    for (int r = 0; r < 4; r++) {
      int qv = (r == 0) ? q4.x : (r == 1) ? q4.y : (r == 2) ? q4.z : q4.w;
      float sm = (qv == myid) ? -1.0f : acc[r];
      if (sm == wv) {
        unsigned kk = (unsigned)(ktg * 16 + g * 4 + r);
        kbest = kbest < kk ? kbest : kk;
      }
    }
  }
  unsigned o1 = __shfl_xor(kbest, 16); kbest = kbest < o1 ? kbest : o1;
  unsigned o2 = __shfl_xor(kbest, 32); kbest = kbest < o2 ? kbest : o2;
  if (lane == 0) idxout[row] = (int)(kbest < (K - 1) ? kbest : (K - 1));
}

// Loss: block handles 8 rows (i0..i0+7) for view v. Thread owns columns
// j=tid and j+256 of the 512-wide logits row.
__global__ __launch_bounds__(256) void loss_k(
    const float* __restrict__ q, const float* __restrict__ invn,
    const int* __restrict__ idxout, const float* __restrict__ w,
    float* __restrict__ lpart) {
  int i0 = blockIdx.x * 8;
  int v = blockIdx.y;
  int tid = threadIdx.x;
  __shared__ float nns[8][D];
  __shared__ float rm[8][4], re[8][4], sdlds[8];
  #pragma unroll
  for (int ii = 0; ii < 4; ii++) {
    int i = ii * 2 + (tid >> 7);
    int d = tid & 127;
    int nnidx = idxout[(v ? 0 : B) + i0 + i];
    nns[i][d] = q[(size_t)d * K + nnidx] * invn[nnidx];
  }
  __syncthreads();
  const float* pr = w + (v ? P1_OFF : P0_OFF);
  const float* r0 = pr + tid * D;
  const float* r1 = pr + (tid + 256) * D;
  float a0[8] = {0, 0, 0, 0, 0, 0, 0, 0};
  float a1[8] = {0, 0, 0, 0, 0, 0, 0, 0};
  for (int d = 0; d < D; d += 4) {
    float4 x0 = *(const float4*)(r0 + d);
    float4 x1 = *(const float4*)(r1 + d);
    #pragma unroll
    for (int i = 0; i < 8; i++) {
      float4 n = *(const float4*)&nns[i][d];
      a0[i] = fmaf(x0.x, n.x, a0[i]); a0[i] = fmaf(x0.y, n.y, a0[i]);
      a0[i] = fmaf(x0.z, n.z, a0[i]); a0[i] = fmaf(x0.w, n.w, a0[i]);
      a1[i] = fmaf(x1.x, n.x, a1[i]); a1[i] = fmaf(x1.y, n.y, a1[i]);
      a1[i] = fmaf(x1.z, n.z, a1[i]); a1[i] = fmaf(x1.w, n.w, a1[i]);
    }
  }
  #pragma unroll
  for (int i = 0; i < 8; i++) {
    a0[i] *= (1.0f / TEMP);
    a1[i] *= (1.0f / TEMP);
  }
  #pragma unroll
  for (int i = 0; i < 8; i++) {
    int ig = i0 + i;
    if ((ig & 256) == 0) { if (tid == ig) sdlds[i] = a0[i]; }
    else { if (tid == (ig & 255)) sdlds[i] = a1[i]; }
  }
  int wv = tid >> 6;
  #pragma unroll
  for (int i = 0; i < 8; i++) {
    float m = fmaxf(a0[i], a1[i]);
    #pragma unroll
    for (int o = 32; o; o >>= 1) m = fmaxf(m, __shfl_xor(m, o));
    if ((tid & 63) == 0) rm[i][wv] = m;
  }
  __syncthreads();
  #pragma unroll
  for (int i = 0; i < 8; i++) {
    float m = fmaxf(fmaxf(rm[i][0], rm[i][1]), fmaxf(rm[i][2], rm[i][3]));
    float e = expf(a0[i] - m) + expf(a1[i] - m);
    #pragma unroll
    for (int o = 32; o; o >>= 1) e += __shfl_xor(e, o);
    if ((tid & 63) == 0) re[i][wv] = e;
  }
  __syncthreads();
  if (tid < 8) {
    int i = tid;
    float m = fmaxf(fmaxf(rm[i][0], rm[i][1]), fmaxf(rm[i][2], rm[i][3]));
    float s = re[i][0] + re[i][1] + re[i][2] + re[i][3];
    lpart[v * B + i0 + i] = sdlds[i] - m - logf(s);
  }
}

// Final: loss = -(sum of 1024 partials)/1024 ; also write new_ptr.
__global__ __launch_bounds__(256) void final_k(
    const float* __restrict__ lpart, float* __restrict__ out) {
  int tid = threadIdx.x;
  float s = lpart[tid] + lpart[tid + 256] + lpart[tid + 512] + lpart[tid + 768];
  #pragma unroll
  for (int o = 32; o; o >>= 1) s += __shfl_xor(s, o);
  __shared__ float sm[4];
  if ((tid & 63) == 0) sm[tid >> 6] = s;
  __syncthreads();
  if (tid == 0) {
    float total = sm[0] + sm[1] + sm[2] + sm[3];
    out[0] = -total * (1.0f / 1024.0f);
    out[1 + D * K + K] = 512.0f;
  }
}

extern "C" void kernel_launch(void* const* d_in, const int* in_sizes, int n_in,
                              void* d_out, int out_size, void* d_ws, size_t ws_size,
                              hipStream_t stream) {
  const float* p0 = (const float*)d_in[0];
  const float* p1 = (const float*)d_in[1];
  const float* z0 = (const float*)d_in[2];
  const float* z1 = (const float*)d_in[3];
  const float* q  = (const float*)d_in[4];
  const int* qid  = (const int*)d_in[5];
  const int* ids  = (const int*)d_in[6];
  float* out = (float*)d_out;
  float* w = (float*)d_ws;
  float* invn = w + INVN_OFF;
  _Float16* zf16 = (_Float16*)(w + ZF16_OFF);
  _Float16* qA   = (_Float16*)(w + QA_OFF);
  float* pval = w + PVAL_OFF;
  int* wkb    = (int*)(w + WKB_OFF);
  float* wval = w + WVAL_OFF;
  int* idxout = (int*)(w + IDX_OFF);
  float* lpart = w + LP_OFF;

  rownorm_k<<<2048, 128, 0, stream>>>(p0, p1, z0, z1, w, zf16);
  colq_k<<<K / 128, 256, 0, stream>>>(q, qid, ids, w + Z0_OFF, invn, out, qA);
  nnsearch_k<<<1024, 256, 0, stream>>>(qA, zf16, qid, ids, pval);
  nnreduce_k<<<1024, 256, 0, stream>>>(pval, wkb, wval);
  nnfix_k<<<256, 256, 0, stream>>>(qA, zf16, qid, ids, wkb, wval, idxout);
  dim3 gl(B / 8, 2);
  loss_k<<<gl, 256, 0, stream>>>(q, invn, idxout, w, lpart);
  final_k<<<1, 256, 0, stream>>>(lpart, out);
}

// Round 11
// 126.864 us; speedup vs baseline: 1.2156x; 1.0054x over previous
//
#include <hip/hip_runtime.h>
#include <hip/hip_bf16.h>

typedef _Float16 half8 __attribute__((ext_vector_type(8)));
typedef _Float16 half4 __attribute__((ext_vector_type(4)));
typedef float f32x4 __attribute__((ext_vector_type(4)));

#define B 512
#define D 128
#define K 131072
#define TEMP 0.07f
#define NKB 256      // k-blocks in nnsearch grid
#define KT_PER 32    // 16-wide k-tiles per block (512 cols)
#define NSS 16       // superstages (2 kt each)

// ws layout in float units
#define INVN_OFF 0
#define Z0_OFF   131072
#define Z1_OFF   196608
#define P0_OFF   262144
#define P1_OFF   327680
#define ZF16_OFF 393216                 // 1024*128 halves = 65536 floats
#define QA_OFF   458752                 // K*D halves = 8388608 floats
#define PVAL_OFF 8847360                // 1024*256 floats
#define IDX_OFF  9373696                // 1024 ints
#define LP_OFF   9374720                // 1024 floats

// Async global->LDS, 16B per lane; LDS dest is wave-uniform base + lane*16.
__device__ __forceinline__ void gload_lds16(const _Float16* g, _Float16* l) {
  __builtin_amdgcn_global_load_lds(
      (const __attribute__((address_space(1))) unsigned int*)g,
      (__attribute__((address_space(3))) unsigned int*)l, 16, 0, 0);
}

// Normalize rows of z0, z1, p0, p1 (each B x D) into ws; also z in f16.
__global__ __launch_bounds__(128) void rownorm_k(
    const float* __restrict__ p0, const float* __restrict__ p1,
    const float* __restrict__ z0, const float* __restrict__ z1,
    float* __restrict__ w, _Float16* __restrict__ zf16) {
  int row = blockIdx.x & (B - 1);
  int which = blockIdx.x >> 9;  // 0..3
  const float* src; float* dst;
  switch (which) {
    case 0: src = z0; dst = w + Z0_OFF; break;
    case 1: src = z1; dst = w + Z1_OFF; break;
    case 2: src = p0; dst = w + P0_OFF; break;
    default: src = p1; dst = w + P1_OFF; break;
  }
  int tid = threadIdx.x;
  float v = src[row * D + tid];
  float s = v * v;
  #pragma unroll
  for (int o = 32; o; o >>= 1) s += __shfl_xor(s, o);
  __shared__ float sm[2];
  if ((tid & 63) == 0) sm[tid >> 6] = s;
  __syncthreads();
  float inv = rsqrtf(sm[0] + sm[1]);
  float nv = v * inv;
  dst[row * D + tid] = nv;
  if (which < 2) zf16[(which * B + row) * D + tid] = (_Float16)nv;
}

// Fused, BW-oriented: block owns 128 queue columns.
// Phase 1: float4 loads along k -> column norms (LDS tree reduce).
// Phase 1.5 (kb>=4): foreign column k0-1 normalized into fcol (psum reuse).
// Phase 2 (kb>=4): shifted window -> ALIGNED float4 out stores:
//   st = {shfl_up(o3), o0, o1, o2} covers cols k0-1+4kc .. k0+2+4kc at
//   flat addr d*K + k0 + 4kc (16B-aligned). Own col k0+127 is written by
//   block kb+1 (block 1023 scalar-stores col K-1). kb<4 keeps old path.
// Phase 3: pack MFMA A-operand fragments (qA) from LDS f16 tile.
__global__ __launch_bounds__(256) void colq_k(
    const float* __restrict__ q, const int* __restrict__ qid,
    const int* __restrict__ ids, const float* __restrict__ w_z0,
    float* __restrict__ invn, float* __restrict__ out,
    _Float16* __restrict__ qA) {
  __shared__ float psum[8][128];
  __shared__ float invs[128];
  __shared__ float s_invm1;
  __shared__ _Float16 tile[128][136];
  int tid = threadIdx.x;
  int kb = blockIdx.x;           // 0..1023
  int k0 = kb * 128;
  int kc = tid & 31, dg = tid >> 5;
  {
    float4 acc = {0.f, 0.f, 0.f, 0.f};
    for (int i = 0; i < 16; i++) {
      int d = dg * 16 + i;
      float4 v = *(const float4*)(q + (size_t)d * K + k0 + kc * 4);
      acc.x = fmaf(v.x, v.x, acc.x); acc.y = fmaf(v.y, v.y, acc.y);
      acc.z = fmaf(v.z, v.z, acc.z); acc.w = fmaf(v.w, v.w, acc.w);
    }
    *(float4*)&psum[dg][kc * 4] = acc;
  }
  __syncthreads();
  if (tid < 128) {
    float s = 0.f;
    #pragma unroll
    for (int g2 = 0; g2 < 8; g2++) s += psum[g2][tid];
    float inv = rsqrtf(s);
    invs[tid] = inv;
    invn[k0 + tid] = inv;
    int kk = k0 + tid;
    out[1 + (size_t)D * K + kk] = (float)((kk < B) ? ids[kk] : qid[kk]);
  }
  __syncthreads();
  // phase 1.5: foreign column (k0-1) values into fcol (aliases psum[0..1])
  float* fq   = &psum[0][0];
  float* fcol = &psum[1][0];
  if (kb == 4) {
    if (tid < 32)
      *(float4*)&fcol[tid * 4] = *(const float4*)(w_z0 + (size_t)511 * D + tid * 4);
  } else if (kb > 4) {
    if (tid < 128) fq[tid] = q[(size_t)tid * K + (k0 - 1)];
    __syncthreads();
    if (tid < 64) {
      float s2 = fq[tid] * fq[tid] + fq[tid + 64] * fq[tid + 64];
      #pragma unroll
      for (int o = 32; o; o >>= 1) s2 += __shfl_xor(s2, o);
      if (tid == 0) s_invm1 = rsqrtf(s2);
    }
    __syncthreads();
    if (tid < 128) fcol[tid] = fq[tid] * s_invm1;
  }
  __syncthreads();
  if (kb >= 4) {
    float4 iv = *(const float4*)&invs[kc * 4];
    for (int i = 0; i < 16; i++) {
      int d = i * 8 + dg;
      float4 v = *(const float4*)(q + (size_t)d * K + k0 + kc * 4);
      float o0 = v.x * iv.x, o1 = v.y * iv.y, o2 = v.z * iv.z, o3 = v.w * iv.w;
      half4 t = {(_Float16)o0, (_Float16)o1, (_Float16)o2, (_Float16)o3};
      *(half4*)&tile[d][kc * 4] = t;
      float p3 = __shfl_up(o3, 1);
      float x0 = (kc == 0) ? fcol[d] : p3;
      float4 st = {x0, o0, o1, o2};
      *(float4*)(out + (size_t)d * K + k0 + kc * 4) = st;
      if (kb == 1023 && kc == 31)
        out[1 + (size_t)d * K + (K - 1)] = o3;
    }
  } else {
    // zblk path (kb 0..3): output cols come from z0^T; strided scalar stores
    float4 iv = *(const float4*)&invs[kc * 4];
    for (int i = 0; i < 16; i++) {
      int d = i * 8 + dg;
      float4 v = *(const float4*)(q + (size_t)d * K + k0 + kc * 4);
      float o0 = v.x * iv.x, o1 = v.y * iv.y, o2 = v.z * iv.z, o3 = v.w * iv.w;
      half4 t = {(_Float16)o0, (_Float16)o1, (_Float16)o2, (_Float16)o3};
      *(half4*)&tile[d][kc * 4] = t;
      float* oc = out + 1 + (size_t)d * K + k0 + kc * 4;
      int col = k0 + kc * 4;
      oc[0] = w_z0[(size_t)(col + 0) * D + d];
      oc[1] = w_z0[(size_t)(col + 1) * D + d];
      oc[2] = w_z0[(size_t)(col + 2) * D + d];
      oc[3] = w_z0[(size_t)(col + 3) * D + d];
    }
  }
  __syncthreads();
  {
    int dc = tid >> 6, l = tid & 63;
    int g = l >> 4, c = l & 15;
    #pragma unroll
    for (int kt = 0; kt < 8; kt++) {
      half8 f;
      #pragma unroll
      for (int i = 0; i < 8; i++) {
        int d = g * 4 + (i & 3) + ((i >> 2) << 4) + dc * 32;
        f[i] = tile[d][kt * 16 + c];
      }
      int ktg = kb * 8 + kt;
      *(half8*)(qA + (size_t)((ktg * 4 + dc) * 64 + l) * 8) = f;
    }
  }
}

// Value-only masked max: 3 VALU ops per element (cmp, cndmask, max).
#define PROCESS(AF, Q4) do { \
  _Pragma("unroll") \
  for (int nt = 0; nt < 4; nt++) { \
    f32x4 acc = {0.f, 0.f, 0.f, 0.f}; \
    _Pragma("unroll") \
    for (int dc = 0; dc < 4; dc++) \
      acc = __builtin_amdgcn_mfma_f32_16x16x32_f16(AF[dc], bf[nt][dc], acc, 0, 0, 0); \
    _Pragma("unroll") \
    for (int r = 0; r < 4; r++) { \
      int qv_ = (r == 0) ? Q4.x : (r == 1) ? Q4.y : (r == 2) ? Q4.z : Q4.w; \
      float sm_ = (qv_ == myid[nt]) ? -1.0f : acc[r]; \
      best[nt] = fmaxf(best[nt], sm_); \
    } \
  } \
} while (0)

// MFMA NN search pass 1. 3-buffer LDS ring, superstage = 2 kt (8KB),
// ONE barrier per superstage, counted vmcnt(2) mid-loop (never 0).
__global__ __launch_bounds__(256) void nnsearch_k(
    const _Float16* __restrict__ qA, const _Float16* __restrict__ zf16,
    const int* __restrict__ qid, const int* __restrict__ ids,
    float* __restrict__ pval) {
  __shared__ __align__(16) _Float16 qtile[3][2][2048];
  __shared__ __align__(16) int qid_lds[512];
  int tid = threadIdx.x;
  int flat = blockIdx.x;        // 0..1023
  int cls = flat & 7;           // XCD under round-robin dispatch
  int kb = cls * 32 + (flat >> 5);
  int rg = (flat >> 3) & 3;
  int wave = tid >> 6, lane = tid & 63;
  int g = lane >> 4, c = lane & 15;
  int rowbase = rg * 256 + wave * 64;
  int kt0 = kb * KT_PER;

  #pragma unroll
  for (int j = 0; j < 2; j++)
    gload_lds16(qA + (size_t)(((kt0 + j) * 4 + wave) * 64 + lane) * 8,
                &qtile[0][j][wave * 512]);
  #pragma unroll
  for (int j = 0; j < 2; j++)
    gload_lds16(qA + (size_t)(((kt0 + 2 + j) * 4 + wave) * 64 + lane) * 8,
                &qtile[1][j][wave * 512]);
  qid_lds[tid] = qid[kb * 512 + tid];
  qid_lds[tid + 256] = qid[kb * 512 + tid + 256];

  half8 bf[4][4];
  int myid[4];
  #pragma unroll
  for (int nt = 0; nt < 4; nt++) {
    int row = rowbase + nt * 16 + c;
    myid[nt] = ids[row & (B - 1)];
    #pragma unroll
    for (int dc = 0; dc < 4; dc++) {
      const _Float16* zr = zf16 + row * D + dc * 32 + g * 4;
      half4 lo = *(const half4*)zr;
      half4 hi = *(const half4*)(zr + 16);
      half8 f = {lo[0], lo[1], lo[2], lo[3], hi[0], hi[1], hi[2], hi[3]};
      bf[nt][dc] = f;
    }
  }
  __syncthreads();   // drains prologue stages + qid_lds writes

  float best[4] = {-2.f, -2.f, -2.f, -2.f};
  int cur = 0;
  for (int s = 0; s < NSS; s++) {
    half8 af0[4], af1[4];
    #pragma unroll
    for (int dc = 0; dc < 4; dc++)
      af0[dc] = *(const half8*)&qtile[cur][0][dc * 512 + lane * 8];
    #pragma unroll
    for (int dc = 0; dc < 4; dc++)
      af1[dc] = *(const half8*)&qtile[cur][1][dc * 512 + lane * 8];
    int4 q4a = *(const int4*)&qid_lds[(s * 2 + 0) * 16 + g * 4];
    int4 q4b = *(const int4*)&qid_lds[(s * 2 + 1) * 16 + g * 4];
    if (s + 2 < NSS) {
      int nbuf = cur + 2; if (nbuf >= 3) nbuf -= 3;
      #pragma unroll
      for (int j = 0; j < 2; j++)
        gload_lds16(qA + (size_t)(((kt0 + (s + 2) * 2 + j) * 4 + wave) * 64 + lane) * 8,
                    &qtile[nbuf][j][wave * 512]);
    }
    PROCESS(af0, q4a);
    PROCESS(af1, q4b);
    if (s < NSS - 1) {
      asm volatile("s_waitcnt lgkmcnt(0)" ::: "memory");
      if (s + 2 < NSS) asm volatile("s_waitcnt vmcnt(2)" ::: "memory");
      else             asm volatile("s_waitcnt vmcnt(0)" ::: "memory");
      __builtin_amdgcn_sched_barrier(0);
      __builtin_amdgcn_s_barrier();
      __builtin_amdgcn_sched_barrier(0);
    }
    cur += 1; if (cur >= 3) cur -= 3;
  }

  #pragma unroll
  for (int nt = 0; nt < 4; nt++) {
    float v = best[nt];
    v = fmaxf(v, __shfl_xor(v, 16));
    v = fmaxf(v, __shfl_xor(v, 32));
    if (g == 0) {
      int row = rowbase + nt * 16 + c;
      pval[row * NKB + kb] = v;
    }
  }
}

// Fused reduce + index recovery. One block per row. Phase A: argmax over
// NKB block-maxima (lossless pack for lowest-kb tie). Phase B: 4 waves
// split the winning block's 32 kt; replicated-row MFMA reproduces bitwise
// identical sims; lowest k with sim == wval wins.
__global__ __launch_bounds__(256) void nnpick_k(
    const float* __restrict__ pval, const _Float16* __restrict__ qA,
    const _Float16* __restrict__ zf16, const int* __restrict__ qid,
    const int* __restrict__ ids, int* __restrict__ idxout) {
  int row = blockIdx.x;
  int tid = threadIdx.x;
  int wave = tid >> 6, lane = tid & 63;
  int g = lane >> 4;
  __shared__ unsigned sv[4];
  __shared__ unsigned skb[4];
  __shared__ int s_kb;
  __shared__ float s_wv;
  {
    float a = pval[row * NKB + tid];
    unsigned v = (__float_as_uint(fmaf(a, 0.5f, 3.0f)) << 9) | (unsigned)(NKB - 1 - tid);
    #pragma unroll
    for (int o = 32; o; o >>= 1) {
      unsigned ov = __shfl_xor(v, o);
      v = v > ov ? v : ov;
    }
    if (lane == 0) sv[wave] = v;
  }
  __syncthreads();
  if (tid == 0) {
    unsigned v = sv[0];
    #pragma unroll
    for (int wv = 1; wv < 4; wv++) v = v > sv[wv] ? v : sv[wv];
    int kbw = (NKB - 1) - (int)(v & 0x1FFu);
    s_kb = kbw;
    s_wv = pval[row * NKB + kbw];
  }
  __syncthreads();
  int kb = s_kb;
  float wv = s_wv;
  int myid = ids[row & (B - 1)];

  half8 bf[4];
  #pragma unroll
  for (int dc = 0; dc < 4; dc++) {
    const _Float16* zr = zf16 + row * D + dc * 32 + g * 4;
    half4 lo = *(const half4*)zr;
    half4 hi = *(const half4*)(zr + 16);
    half8 f = {lo[0], lo[1], lo[2], lo[3], hi[0], hi[1], hi[2], hi[3]};
    bf[dc] = f;
  }

  unsigned kbest = 0x7FFFFFFFu;
  int ktbase = kb * KT_PER + wave * 8;
  for (int kt = 0; kt < 8; kt++) {
    int ktg = ktbase + kt;
    half8 af[4];
    #pragma unroll
    for (int dc = 0; dc < 4; dc++)
      af[dc] = *(const half8*)(qA + (size_t)((ktg * 4 + dc) * 64 + lane) * 8);
    int4 q4 = *(const int4*)(qid + ktg * 16 + g * 4);
    f32x4 acc = {0.f, 0.f, 0.f, 0.f};
    #pragma unroll
    for (int dc = 0; dc < 4; dc++)
      acc = __builtin_amdgcn_mfma_f32_16x16x32_f16(af[dc], bf[dc], acc, 0, 0, 0);
    #pragma unroll
    for (int r = 0; r < 4; r++) {
      int qv = (r == 0) ? q4.x : (r == 1) ? q4.y : (r == 2) ? q4.z : q4.w;
      float sm = (qv == myid) ? -1.0f : acc[r];
      if (sm == wv) {
        unsigned kk = (unsigned)(ktg * 16 + g * 4 + r);
        kbest = kbest < kk ? kbest : kk;
      }
    }
  }
  unsigned o1 = __shfl_xor(kbest, 16); kbest = kbest < o1 ? kbest : o1;
  unsigned o2 = __shfl_xor(kbest, 32); kbest = kbest < o2 ? kbest : o2;
  if (lane == 0) skb[wave] = kbest;
  __syncthreads();
  if (tid == 0) {
    unsigned v = skb[0];
    #pragma unroll
    for (int wv2 = 1; wv2 < 4; wv2++) v = v < skb[wv2] ? v : skb[wv2];
    idxout[row] = (int)(v < (K - 1) ? v : (K - 1));
  }
}

// Loss: block handles 8 rows (i0..i0+7) for view v. Thread owns columns
// j=tid and j+256 of the 512-wide logits row.
__global__ __launch_bounds__(256) void loss_k(
    const float* __restrict__ q, const float* __restrict__ invn,
    const int* __restrict__ idxout, const float* __restrict__ w,
    float* __restrict__ lpart) {
  int i0 = blockIdx.x * 8;
  int v = blockIdx.y;
  int tid = threadIdx.x;
  __shared__ float nns[8][D];
  __shared__ float rm[8][4], re[8][4], sdlds[8];
  #pragma unroll
  for (int ii = 0; ii < 4; ii++) {
    int i = ii * 2 + (tid >> 7);
    int d = tid & 127;
    int nnidx = idxout[(v ? 0 : B) + i0 + i];
    nns[i][d] = q[(size_t)d * K + nnidx] * invn[nnidx];
  }
  __syncthreads();
  const float* pr = w + (v ? P1_OFF : P0_OFF);
  const float* r0 = pr + tid * D;
  const float* r1 = pr + (tid + 256) * D;
  float a0[8] = {0, 0, 0, 0, 0, 0, 0, 0};
  float a1[8] = {0, 0, 0, 0, 0, 0, 0, 0};
  for (int d = 0; d < D; d += 4) {
    float4 x0 = *(const float4*)(r0 + d);
    float4 x1 = *(const float4*)(r1 + d);
    #pragma unroll
    for (int i = 0; i < 8; i++) {
      float4 n = *(const float4*)&nns[i][d];
      a0[i] = fmaf(x0.x, n.x, a0[i]); a0[i] = fmaf(x0.y, n.y, a0[i]);
      a0[i] = fmaf(x0.z, n.z, a0[i]); a0[i] = fmaf(x0.w, n.w, a0[i]);
      a1[i] = fmaf(x1.x, n.x, a1[i]); a1[i] = fmaf(x1.y, n.y, a1[i]);
      a1[i] = fmaf(x1.z, n.z, a1[i]); a1[i] = fmaf(x1.w, n.w, a1[i]);
    }
  }
  #pragma unroll
  for (int i = 0; i < 8; i++) {
    a0[i] *= (1.0f / TEMP);
    a1[i] *= (1.0f / TEMP);
  }
  #pragma unroll
  for (int i = 0; i < 8; i++) {
    int ig = i0 + i;
    if ((ig & 256) == 0) { if (tid == ig) sdlds[i] = a0[i]; }
    else { if (tid == (ig & 255)) sdlds[i] = a1[i]; }
  }
  int wv = tid >> 6;
  #pragma unroll
  for (int i = 0; i < 8; i++) {
    float m = fmaxf(a0[i], a1[i]);
    #pragma unroll
    for (int o = 32; o; o >>= 1) m = fmaxf(m, __shfl_xor(m, o));
    if ((tid & 63) == 0) rm[i][wv] = m;
  }
  __syncthreads();
  #pragma unroll
  for (int i = 0; i < 8; i++) {
    float m = fmaxf(fmaxf(rm[i][0], rm[i][1]), fmaxf(rm[i][2], rm[i][3]));
    float e = expf(a0[i] - m) + expf(a1[i] - m);
    #pragma unroll
    for (int o = 32; o; o >>= 1) e += __shfl_xor(e, o);
    if ((tid & 63) == 0) re[i][wv] = e;
  }
  __syncthreads();
  if (tid < 8) {
    int i = tid;
    float m = fmaxf(fmaxf(rm[i][0], rm[i][1]), fmaxf(rm[i][2], rm[i][3]));
    float s = re[i][0] + re[i][1] + re[i][2] + re[i][3];
    lpart[v * B + i0 + i] = sdlds[i] - m - logf(s);
  }
}

// Final: loss = -(sum of 1024 partials)/1024 ; also write new_ptr.
__global__ __launch_bounds__(256) void final_k(
    const float* __restrict__ lpart, float* __restrict__ out) {
  int tid = threadIdx.x;
  float s = lpart[tid] + lpart[tid + 256] + lpart[tid + 512] + lpart[tid + 768];
  #pragma unroll
  for (int o = 32; o; o >>= 1) s += __shfl_xor(s, o);
  __shared__ float sm[4];
  if ((tid & 63) == 0) sm[tid >> 6] = s;
  __syncthreads();
  if (tid == 0) {
    float total = sm[0] + sm[1] + sm[2] + sm[3];
    out[0] = -total * (1.0f / 1024.0f);
    out[1 + D * K + K] = 512.0f;
  }
}

extern "C" void kernel_launch(void* const* d_in, const int* in_sizes, int n_in,
                              void* d_out, int out_size, void* d_ws, size_t ws_size,
                              hipStream_t stream) {
  const float* p0 = (const float*)d_in[0];
  const float* p1 = (const float*)d_in[1];
  const float* z0 = (const float*)d_in[2];
  const float* z1 = (const float*)d_in[3];
  const float* q  = (const float*)d_in[4];
  const int* qid  = (const int*)d_in[5];
  const int* ids  = (const int*)d_in[6];
  float* out = (float*)d_out;
  float* w = (float*)d_ws;
  float* invn = w + INVN_OFF;
  _Float16* zf16 = (_Float16*)(w + ZF16_OFF);
  _Float16* qA   = (_Float16*)(w + QA_OFF);
  float* pval = w + PVAL_OFF;
  int* idxout = (int*)(w + IDX_OFF);
  float* lpart = w + LP_OFF;

  rownorm_k<<<2048, 128, 0, stream>>>(p0, p1, z0, z1, w, zf16);
  colq_k<<<K / 128, 256, 0, stream>>>(q, qid, ids, w + Z0_OFF, invn, out, qA);
  nnsearch_k<<<1024, 256, 0, stream>>>(qA, zf16, qid, ids, pval);
  nnpick_k<<<1024, 256, 0, stream>>>(pval, qA, zf16, qid, ids, idxout);
  dim3 gl(B / 8, 2);
  loss_k<<<gl, 256, 0, stream>>>(q, invn, idxout, w, lpart);
  final_k<<<1, 256, 0, stream>>>(lpart, out);
}

// Round 12
// 113.906 us; speedup vs baseline: 1.3538x; 1.1138x over previous
//
#include <hip/hip_runtime.h>
#include <hip/hip_bf16.h>

typedef _Float16 half8 __attribute__((ext_vector_type(8)));
typedef _Float16 half4 __attribute__((ext_vector_type(4)));
typedef float f32x4 __attribute__((ext_vector_type(4)));

#define B 512
#define D 128
#define K 131072
#define TEMP 0.07f
#define NKB 256      // k-blocks in nnsearch grid
#define KT_PER 32    // 16-wide k-tiles per block (512 cols)
#define NSS 16       // superstages (2 kt each)

// ws layout in float units
#define INVN_OFF 0
#define Z0_OFF   131072
#define Z1_OFF   196608
#define P0_OFF   262144
#define P1_OFF   327680
#define ZF16_OFF 393216                 // 1024*128 halves = 65536 floats
#define QA_OFF   458752                 // K*D halves = 8388608 floats
#define PVAL_OFF 8847360                // 1024*256 floats
#define IDX_OFF  9373696                // 1024 ints
#define LP_OFF   9374720                // 1024 floats

// Async global->LDS, 16B per lane; LDS dest is wave-uniform base + lane*16.
__device__ __forceinline__ void gload_lds16(const _Float16* g, _Float16* l) {
  __builtin_amdgcn_global_load_lds(
      (const __attribute__((address_space(1))) unsigned int*)g,
      (__attribute__((address_space(3))) unsigned int*)l, 16, 0, 0);
}

// Normalize rows of z0, z1, p0, p1 (each B x D) into ws; also z in f16.
__global__ __launch_bounds__(128) void rownorm_k(
    const float* __restrict__ p0, const float* __restrict__ p1,
    const float* __restrict__ z0, const float* __restrict__ z1,
    float* __restrict__ w, _Float16* __restrict__ zf16) {
  int row = blockIdx.x & (B - 1);
  int which = blockIdx.x >> 9;  // 0..3
  const float* src; float* dst;
  switch (which) {
    case 0: src = z0; dst = w + Z0_OFF; break;
    case 1: src = z1; dst = w + Z1_OFF; break;
    case 2: src = p0; dst = w + P0_OFF; break;
    default: src = p1; dst = w + P1_OFF; break;
  }
  int tid = threadIdx.x;
  float v = src[row * D + tid];
  float s = v * v;
  #pragma unroll
  for (int o = 32; o; o >>= 1) s += __shfl_xor(s, o);
  __shared__ float sm[2];
  if ((tid & 63) == 0) sm[tid >> 6] = s;
  __syncthreads();
  float inv = rsqrtf(sm[0] + sm[1]);
  float nv = v * inv;
  dst[row * D + tid] = nv;
  if (which < 2) zf16[(which * B + row) * D + tid] = (_Float16)nv;
}

// Fused, single-pass register-resident: block owns 128 queue columns.
// Phase 1: 16 float4 loads (kept in 64 VGPRs) -> column norms via LDS tree.
// Phase 2: outputs computed FROM REGISTERS (no global re-read): aligned
//   float4 out stores via shifted window {shfl_up(o3), o0, o1, o2}; f16
//   tile writes for the pack. Foreign col k0-1 loaded once at kernel start.
// Phase 3: pack MFMA A-operand fragments (qA) from LDS f16 tile.
__global__ __launch_bounds__(256) void colq_k(
    const float* __restrict__ q, const int* __restrict__ qid,
    const int* __restrict__ ids, const float* __restrict__ w_z0,
    float* __restrict__ invn, float* __restrict__ out,
    _Float16* __restrict__ qA) {
  __shared__ float psum[8][128];
  __shared__ float invs[128];
  __shared__ float sm2[2];
  __shared__ float fcol[128];
  __shared__ _Float16 tile[128][136];
  int tid = threadIdx.x;
  int kb = blockIdx.x;           // 0..1023
  int k0 = kb * 128;
  int kc = tid & 31, dg = tid >> 5;

  // phase 0: foreign column k0-1 (one scalar per tid<128), overlaps phase 1
  float fqv = 0.f;
  if (kb > 4 && tid < 128) fqv = q[(size_t)tid * K + (k0 - 1)];

  // phase 1: cold read of the block's 64KB tile into registers
  float4 v[16];
  {
    float4 acc = {0.f, 0.f, 0.f, 0.f};
    #pragma unroll
    for (int i = 0; i < 16; i++) {
      int d = dg * 16 + i;
      v[i] = *(const float4*)(q + (size_t)d * K + k0 + kc * 4);
      acc.x = fmaf(v[i].x, v[i].x, acc.x); acc.y = fmaf(v[i].y, v[i].y, acc.y);
      acc.z = fmaf(v[i].z, v[i].z, acc.z); acc.w = fmaf(v[i].w, v[i].w, acc.w);
    }
    *(float4*)&psum[dg][kc * 4] = acc;
  }
  __syncthreads();
  if (tid < 128) {
    float s = 0.f;
    #pragma unroll
    for (int g2 = 0; g2 < 8; g2++) s += psum[g2][tid];
    float inv = rsqrtf(s);
    invs[tid] = inv;
    invn[k0 + tid] = inv;
    int kk = k0 + tid;
    out[1 + (size_t)D * K + kk] = (float)((kk < B) ? ids[kk] : qid[kk]);
  }
  if (kb > 4 && tid < 128) {
    float s2 = fqv * fqv;
    #pragma unroll
    for (int o = 32; o; o >>= 1) s2 += __shfl_xor(s2, o);
    if ((tid & 63) == 0) sm2[tid >> 6] = s2;
  }
  __syncthreads();
  if (kb > 4) {
    if (tid < 128) fcol[tid] = fqv * rsqrtf(sm2[0] + sm2[1]);
  } else if (kb == 4) {
    if (tid < 32)
      *(float4*)&fcol[tid * 4] = *(const float4*)(w_z0 + (size_t)511 * D + tid * 4);
  }
  __syncthreads();

  // phase 2: pure compute+store from registers
  float4 iv = *(const float4*)&invs[kc * 4];
  if (kb >= 4) {
    #pragma unroll
    for (int i = 0; i < 16; i++) {
      int d = dg * 16 + i;
      float o0 = v[i].x * iv.x, o1 = v[i].y * iv.y;
      float o2 = v[i].z * iv.z, o3 = v[i].w * iv.w;
      half4 t = {(_Float16)o0, (_Float16)o1, (_Float16)o2, (_Float16)o3};
      *(half4*)&tile[d][kc * 4] = t;
      float p3 = __shfl_up(o3, 1);
      float x0 = (kc == 0) ? fcol[d] : p3;
      float4 st = {x0, o0, o1, o2};
      *(float4*)(out + (size_t)d * K + k0 + kc * 4) = st;
      if (kb == 1023 && kc == 31)
        out[1 + (size_t)d * K + (K - 1)] = o3;
    }
  } else {
    // zblk path (kb 0..3): output cols come from z0^T (strided loads, 4 blocks)
    #pragma unroll
    for (int i = 0; i < 16; i++) {
      int d = dg * 16 + i;
      float o0 = v[i].x * iv.x, o1 = v[i].y * iv.y;
      float o2 = v[i].z * iv.z, o3 = v[i].w * iv.w;
      half4 t = {(_Float16)o0, (_Float16)o1, (_Float16)o2, (_Float16)o3};
      *(half4*)&tile[d][kc * 4] = t;
      float* oc = out + 1 + (size_t)d * K + k0 + kc * 4;
      int col = k0 + kc * 4;
      oc[0] = w_z0[(size_t)(col + 0) * D + d];
      oc[1] = w_z0[(size_t)(col + 1) * D + d];
      oc[2] = w_z0[(size_t)(col + 2) * D + d];
      oc[3] = w_z0[(size_t)(col + 3) * D + d];
    }
  }
  __syncthreads();
  {
    int dc = tid >> 6, l = tid & 63;
    int g = l >> 4, c = l & 15;
    #pragma unroll
    for (int kt = 0; kt < 8; kt++) {
      half8 f;
      #pragma unroll
      for (int i = 0; i < 8; i++) {
        int d = g * 4 + (i & 3) + ((i >> 2) << 4) + dc * 32;
        f[i] = tile[d][kt * 16 + c];
      }
      int ktg = kb * 8 + kt;
      *(half8*)(qA + (size_t)((ktg * 4 + dc) * 64 + l) * 8) = f;
    }
  }
}

// Value-only masked max: 3 VALU ops per element (cmp, cndmask, max).
#define PROCESS(AF, Q4) do { \
  _Pragma("unroll") \
  for (int nt = 0; nt < 4; nt++) { \
    f32x4 acc = {0.f, 0.f, 0.f, 0.f}; \
    _Pragma("unroll") \
    for (int dc = 0; dc < 4; dc++) \
      acc = __builtin_amdgcn_mfma_f32_16x16x32_f16(AF[dc], bf[nt][dc], acc, 0, 0, 0); \
    _Pragma("unroll") \
    for (int r = 0; r < 4; r++) { \
      int qv_ = (r == 0) ? Q4.x : (r == 1) ? Q4.y : (r == 2) ? Q4.z : Q4.w; \
      float sm_ = (qv_ == myid[nt]) ? -1.0f : acc[r]; \
      best[nt] = fmaxf(best[nt], sm_); \
    } \
  } \
} while (0)

// MFMA NN search pass 1. 3-buffer LDS ring, superstage = 2 kt (8KB),
// ONE barrier per superstage, counted vmcnt(2) mid-loop (never 0).
__global__ __launch_bounds__(256) void nnsearch_k(
    const _Float16* __restrict__ qA, const _Float16* __restrict__ zf16,
    const int* __restrict__ qid, const int* __restrict__ ids,
    float* __restrict__ pval) {
  __shared__ __align__(16) _Float16 qtile[3][2][2048];
  __shared__ __align__(16) int qid_lds[512];
  int tid = threadIdx.x;
  int flat = blockIdx.x;        // 0..1023
  int cls = flat & 7;           // XCD under round-robin dispatch
  int kb = cls * 32 + (flat >> 5);
  int rg = (flat >> 3) & 3;
  int wave = tid >> 6, lane = tid & 63;
  int g = lane >> 4, c = lane & 15;
  int rowbase = rg * 256 + wave * 64;
  int kt0 = kb * KT_PER;

  #pragma unroll
  for (int j = 0; j < 2; j++)
    gload_lds16(qA + (size_t)(((kt0 + j) * 4 + wave) * 64 + lane) * 8,
                &qtile[0][j][wave * 512]);
  #pragma unroll
  for (int j = 0; j < 2; j++)
    gload_lds16(qA + (size_t)(((kt0 + 2 + j) * 4 + wave) * 64 + lane) * 8,
                &qtile[1][j][wave * 512]);
  qid_lds[tid] = qid[kb * 512 + tid];
  qid_lds[tid + 256] = qid[kb * 512 + tid + 256];

  half8 bf[4][4];
  int myid[4];
  #pragma unroll
  for (int nt = 0; nt < 4; nt++) {
    int row = rowbase + nt * 16 + c;
    myid[nt] = ids[row & (B - 1)];
    #pragma unroll
    for (int dc = 0; dc < 4; dc++) {
      const _Float16* zr = zf16 + row * D + dc * 32 + g * 4;
      half4 lo = *(const half4*)zr;
      half4 hi = *(const half4*)(zr + 16);
      half8 f = {lo[0], lo[1], lo[2], lo[3], hi[0], hi[1], hi[2], hi[3]};
      bf[nt][dc] = f;
    }
  }
  __syncthreads();   // drains prologue stages + qid_lds writes

  float best[4] = {-2.f, -2.f, -2.f, -2.f};
  int cur = 0;
  for (int s = 0; s < NSS; s++) {
    half8 af0[4], af1[4];
    #pragma unroll
    for (int dc = 0; dc < 4; dc++)
      af0[dc] = *(const half8*)&qtile[cur][0][dc * 512 + lane * 8];
    #pragma unroll
    for (int dc = 0; dc < 4; dc++)
      af1[dc] = *(const half8*)&qtile[cur][1][dc * 512 + lane * 8];
    int4 q4a = *(const int4*)&qid_lds[(s * 2 + 0) * 16 + g * 4];
    int4 q4b = *(const int4*)&qid_lds[(s * 2 + 1) * 16 + g * 4];
    if (s + 2 < NSS) {
      int nbuf = cur + 2; if (nbuf >= 3) nbuf -= 3;
      #pragma unroll
      for (int j = 0; j < 2; j++)
        gload_lds16(qA + (size_t)(((kt0 + (s + 2) * 2 + j) * 4 + wave) * 64 + lane) * 8,
                    &qtile[nbuf][j][wave * 512]);
    }
    PROCESS(af0, q4a);
    PROCESS(af1, q4b);
    if (s < NSS - 1) {
      asm volatile("s_waitcnt lgkmcnt(0)" ::: "memory");
      if (s + 2 < NSS) asm volatile("s_waitcnt vmcnt(2)" ::: "memory");
      else             asm volatile("s_waitcnt vmcnt(0)" ::: "memory");
      __builtin_amdgcn_sched_barrier(0);
      __builtin_amdgcn_s_barrier();
      __builtin_amdgcn_sched_barrier(0);
    }
    cur += 1; if (cur >= 3) cur -= 3;
  }

  #pragma unroll
  for (int nt = 0; nt < 4; nt++) {
    float v = best[nt];
    v = fmaxf(v, __shfl_xor(v, 16));
    v = fmaxf(v, __shfl_xor(v, 32));
    if (g == 0) {
      int row = rowbase + nt * 16 + c;
      pval[row * NKB + kb] = v;
    }
  }
}

// Fused reduce + index recovery. One block per row. Phase A: argmax over
// NKB block-maxima (lossless pack for lowest-kb tie). Phase B: 4 waves
// split the winning block's 32 kt; replicated-row MFMA reproduces bitwise
// identical sims; lowest k with sim == wval wins.
__global__ __launch_bounds__(256) void nnpick_k(
    const float* __restrict__ pval, const _Float16* __restrict__ qA,
    const _Float16* __restrict__ zf16, const int* __restrict__ qid,
    const int* __restrict__ ids, int* __restrict__ idxout) {
  int row = blockIdx.x;
  int tid = threadIdx.x;
  int wave = tid >> 6, lane = tid & 63;
  int g = lane >> 4;
  __shared__ unsigned sv[4];
  __shared__ unsigned skb[4];
  __shared__ int s_kb;
  __shared__ float s_wv;
  {
    float a = pval[row * NKB + tid];
    unsigned v = (__float_as_uint(fmaf(a, 0.5f, 3.0f)) << 9) | (unsigned)(NKB - 1 - tid);
    #pragma unroll
    for (int o = 32; o; o >>= 1) {
      unsigned ov = __shfl_xor(v, o);
      v = v > ov ? v : ov;
    }
    if (lane == 0) sv[wave] = v;
  }
  __syncthreads();
  if (tid == 0) {
    unsigned v = sv[0];
    #pragma unroll
    for (int wv = 1; wv < 4; wv++) v = v > sv[wv] ? v : sv[wv];
    int kbw = (NKB - 1) - (int)(v & 0x1FFu);
    s_kb = kbw;
    s_wv = pval[row * NKB + kbw];
  }
  __syncthreads();
  int kb = s_kb;
  float wv = s_wv;
  int myid = ids[row & (B - 1)];

  half8 bf[4];
  #pragma unroll
  for (int dc = 0; dc < 4; dc++) {
    const _Float16* zr = zf16 + row * D + dc * 32 + g * 4;
    half4 lo = *(const half4*)zr;
    half4 hi = *(const half4*)(zr + 16);
    half8 f = {lo[0], lo[1], lo[2], lo[3], hi[0], hi[1], hi[2], hi[3]};
    bf[dc] = f;
  }

  unsigned kbest = 0x7FFFFFFFu;
  int ktbase = kb * KT_PER + wave * 8;
  for (int kt = 0; kt < 8; kt++) {
    int ktg = ktbase + kt;
    half8 af[4];
    #pragma unroll
    for (int dc = 0; dc < 4; dc++)
      af[dc] = *(const half8*)(qA + (size_t)((ktg * 4 + dc) * 64 + lane) * 8);
    int4 q4 = *(const int4*)(qid + ktg * 16 + g * 4);
    f32x4 acc = {0.f, 0.f, 0.f, 0.f};
    #pragma unroll
    for (int dc = 0; dc < 4; dc++)
      acc = __builtin_amdgcn_mfma_f32_16x16x32_f16(af[dc], bf[dc], acc, 0, 0, 0);
    #pragma unroll
    for (int r = 0; r < 4; r++) {
      int qv = (r == 0) ? q4.x : (r == 1) ? q4.y : (r == 2) ? q4.z : q4.w;
      float sm = (qv == myid) ? -1.0f : acc[r];
      if (sm == wv) {
        unsigned kk = (unsigned)(ktg * 16 + g * 4 + r);
        kbest = kbest < kk ? kbest : kk;
      }
    }
  }
  unsigned o1 = __shfl_xor(kbest, 16); kbest = kbest < o1 ? kbest : o1;
  unsigned o2 = __shfl_xor(kbest, 32); kbest = kbest < o2 ? kbest : o2;
  if (lane == 0) skb[wave] = kbest;
  __syncthreads();
  if (tid == 0) {
    unsigned v = skb[0];
    #pragma unroll
    for (int wv2 = 1; wv2 < 4; wv2++) v = v < skb[wv2] ? v : skb[wv2];
    idxout[row] = (int)(v < (K - 1) ? v : (K - 1));
  }
}

// Loss: block handles 8 rows (i0..i0+7) for view v. Thread owns columns
// j=tid and j+256 of the 512-wide logits row.
__global__ __launch_bounds__(256) void loss_k(
    const float* __restrict__ q, const float* __restrict__ invn,
    const int* __restrict__ idxout, const float* __restrict__ w,
    float* __restrict__ lpart) {
  int i0 = blockIdx.x * 8;
  int v = blockIdx.y;
  int tid = threadIdx.x;
  __shared__ float nns[8][D];
  __shared__ float rm[8][4], re[8][4], sdlds[8];
  #pragma unroll
  for (int ii = 0; ii < 4; ii++) {
    int i = ii * 2 + (tid >> 7);
    int d = tid & 127;
    int nnidx = idxout[(v ? 0 : B) + i0 + i];
    nns[i][d] = q[(size_t)d * K + nnidx] * invn[nnidx];
  }
  __syncthreads();
  const float* pr = w + (v ? P1_OFF : P0_OFF);
  const float* r0 = pr + tid * D;
  const float* r1 = pr + (tid + 256) * D;
  float a0[8] = {0, 0, 0, 0, 0, 0, 0, 0};
  float a1[8] = {0, 0, 0, 0, 0, 0, 0, 0};
  for (int d = 0; d < D; d += 4) {
    float4 x0 = *(const float4*)(r0 + d);
    float4 x1 = *(const float4*)(r1 + d);
    #pragma unroll
    for (int i = 0; i < 8; i++) {
      float4 n = *(const float4*)&nns[i][d];
      a0[i] = fmaf(x0.x, n.x, a0[i]); a0[i] = fmaf(x0.y, n.y, a0[i]);
      a0[i] = fmaf(x0.z, n.z, a0[i]); a0[i] = fmaf(x0.w, n.w, a0[i]);
      a1[i] = fmaf(x1.x, n.x, a1[i]); a1[i] = fmaf(x1.y, n.y, a1[i]);
      a1[i] = fmaf(x1.z, n.z, a1[i]); a1[i] = fmaf(x1.w, n.w, a1[i]);
    }
  }
  #pragma unroll
  for (int i = 0; i < 8; i++) {
    a0[i] *= (1.0f / TEMP);
    a1[i] *= (1.0f / TEMP);
  }
  #pragma unroll
  for (int i = 0; i < 8; i++) {
    int ig = i0 + i;
    if ((ig & 256) == 0) { if (tid == ig) sdlds[i] = a0[i]; }
    else { if (tid == (ig & 255)) sdlds[i] = a1[i]; }
  }
  int wv = tid >> 6;
  #pragma unroll
  for (int i = 0; i < 8; i++) {
    float m = fmaxf(a0[i], a1[i]);
    #pragma unroll
    for (int o = 32; o; o >>= 1) m = fmaxf(m, __shfl_xor(m, o));
    if ((tid & 63) == 0) rm[i][wv] = m;
  }
  __syncthreads();
  #pragma unroll
  for (int i = 0; i < 8; i++) {
    float m = fmaxf(fmaxf(rm[i][0], rm[i][1]), fmaxf(rm[i][2], rm[i][3]));
    float e = expf(a0[i] - m) + expf(a1[i] - m);
    #pragma unroll
    for (int o = 32; o; o >>= 1) e += __shfl_xor(e, o);
    if ((tid & 63) == 0) re[i][wv] = e;
  }
  __syncthreads();
  if (tid < 8) {
    int i = tid;
    float m = fmaxf(fmaxf(rm[i][0], rm[i][1]), fmaxf(rm[i][2], rm[i][3]));
    float s = re[i][0] + re[i][1] + re[i][2] + re[i][3];
    lpart[v * B + i0 + i] = sdlds[i] - m - logf(s);
  }
}

// Final: loss = -(sum of 1024 partials)/1024 ; also write new_ptr.
__global__ __launch_bounds__(256) void final_k(
    const float* __restrict__ lpart, float* __restrict__ out) {
  int tid = threadIdx.x;
  float s = lpart[tid] + lpart[tid + 256] + lpart[tid + 512] + lpart[tid + 768];
  #pragma unroll
  for (int o = 32; o; o >>= 1) s += __shfl_xor(s, o);
  __shared__ float sm[4];
  if ((tid & 63) == 0) sm[tid >> 6] = s;
  __syncthreads();
  if (tid == 0) {
    float total = sm[0] + sm[1] + sm[2] + sm[3];
    out[0] = -total * (1.0f / 1024.0f);
    out[1 + D * K + K] = 512.0f;
  }
}

extern "C" void kernel_launch(void* const* d_in, const int* in_sizes, int n_in,
                              void* d_out, int out_size, void* d_ws, size_t ws_size,
                              hipStream_t stream) {
  const float* p0 = (const float*)d_in[0];
  const float* p1 = (const float*)d_in[1];
  const float* z0 = (const float*)d_in[2];
  const float* z1 = (const float*)d_in[3];
  const float* q  = (const float*)d_in[4];
  const int* qid  = (const int*)d_in[5];
  const int* ids  = (const int*)d_in[6];
  float* out = (float*)d_out;
  float* w = (float*)d_ws;
  float* invn = w + INVN_OFF;
  _Float16* zf16 = (_Float16*)(w + ZF16_OFF);
  _Float16* qA   = (_Float16*)(w + QA_OFF);
  float* pval = w + PVAL_OFF;
  int* idxout = (int*)(w + IDX_OFF);
  float* lpart = w + LP_OFF;

  rownorm_k<<<2048, 128, 0, stream>>>(p0, p1, z0, z1, w, zf16);
  colq_k<<<K / 128, 256, 0, stream>>>(q, qid, ids, w + Z0_OFF, invn, out, qA);
  nnsearch_k<<<1024, 256, 0, stream>>>(qA, zf16, qid, ids, pval);
  nnpick_k<<<1024, 256, 0, stream>>>(pval, qA, zf16, qid, ids, idxout);
  dim3 gl(B / 8, 2);
  loss_k<<<gl, 256, 0, stream>>>(q, invn, idxout, w, lpart);
  final_k<<<1, 256, 0, stream>>>(lpart, out);
}